// Round 4
// baseline (374.447 us; speedup 1.0000x reference)
//
#include <hip/hip_runtime.h>
#include <math.h>
#include <stdint.h>

#define B_SZ   2
#define N_PTS  8192
#define IN_DIM 64
#define D_IN   70          // 64 features + 6 geom
#define ODIM   128
#define NQ_ALL (B_SZ * N_PTS)
#define RADIUS_F 0.02f

#define GDIM  32
#define NCELL (GDIM * GDIM * GDIM)
#define HCELL 0.03125f     // 1/32, exact in f32

#define SUP     6                       // base cells per supercell axis
#define NSUP_AX 6                       // ceil(32/6)
#define NSUPER  (NSUP_AX * NSUP_AX * NSUP_AX)
#define SCAP    544                     // staged halo capacity (lambda 432 + 5 sigma)
#define BUF_CAP 52                      // per-lane collect buffer (lambda 28 + 4.5 sigma)
#define MAXROWS 144                     // 12x12 halo (z,y) rows max

typedef unsigned long long u64;

// ---------------------------------------------------------------------------
__device__ __forceinline__ void insert11(u64 (&best)[11], u64 key) {
#pragma unroll
  for (int j = 10; j >= 1; --j) {
    u64 hi = (best[j - 1] > key) ? best[j - 1] : key;
    best[j] = (best[j] < hi) ? best[j] : hi;
  }
  best[0] = (best[0] < key) ? best[0] : key;
}
__device__ __forceinline__ void insert10(u64 (&best)[10], u64 key) {
#pragma unroll
  for (int j = 9; j >= 1; --j) {
    u64 hi = (best[j - 1] > key) ? best[j - 1] : key;
    best[j] = (best[j] < hi) ? best[j] : hi;
  }
  best[0] = (best[0] < key) ? best[0] : key;
}

// exact f32 helpers matching the reference's op order (no contraction)
__device__ __forceinline__ float sq3(float x, float y, float z) {
  return __fadd_rn(__fadd_rn(__fmul_rn(x, x), __fmul_rn(y, y)), __fmul_rn(z, z));
}

__device__ __forceinline__ int cellOf(float v) {
  int c = (int)(v * 32.0f);
  return min(max(c, 0), GDIM - 1);
}

// shared epilogue: covariance over the 10 NN (exact f64) + eigen + geometry
__device__ __forceinline__ void geom_epilogue(const float* __restrict__ P,
                                              const int (&idxs)[10], float dens,
                                              float px, float py, float pz,
                                              float4 ctr, float* __restrict__ g) {
  double c00 = 0, c01 = 0, c02 = 0, c11 = 0, c12 = 0, c22 = 0;
#pragma unroll
  for (int j = 0; j < 10; ++j) {
    const int idx = idxs[j];
    const float nx = P[3 * idx + 0], ny = P[3 * idx + 1], nz = P[3 * idx + 2];
    const float ex = __fsub_rn(nx, px);
    const float ey = __fsub_rn(ny, py);
    const float ez = __fsub_rn(nz, pz);
    c00 += (double)ex * ex; c01 += (double)ex * ey; c02 += (double)ex * ez;
    c11 += (double)ey * ey; c12 += (double)ey * ez; c22 += (double)ez * ez;
  }
  const double a00 = c00 / 10.0, a01 = c01 / 10.0, a02 = c02 / 10.0;
  const double a11 = c11 / 10.0, a12 = c12 / 10.0, a22 = c22 / 10.0;

  double p1 = a01 * a01 + a02 * a02 + a12 * a12;
  double qq = (a00 + a11 + a22) / 3.0;
  double p2 = (a00 - qq) * (a00 - qq) + (a11 - qq) * (a11 - qq) +
              (a22 - qq) * (a22 - qq) + 2.0 * p1;
  double ev0, ev2;
  if (p2 <= 1e-60) {
    ev0 = ev2 = qq;
  } else {
    double p = sqrt(p2 / 6.0);
    double invp = 1.0 / p;
    double b00 = (a00 - qq) * invp, b11 = (a11 - qq) * invp, b22 = (a22 - qq) * invp;
    double b01 = a01 * invp, b02 = a02 * invp, b12 = a12 * invp;
    double detB = b00 * (b11 * b22 - b12 * b12) - b01 * (b01 * b22 - b12 * b02) +
                  b02 * (b01 * b12 - b11 * b02);
    double r = 0.5 * detB;
    r = fmin(1.0, fmax(-1.0, r));
    double phi = acos(r) / 3.0;
    ev2 = qq + 2.0 * p * cos(phi);
    ev0 = qq + 2.0 * p * cos(phi + 2.0943951023931953);  // +2*pi/3
  }
  const float curv = (float)(ev0 / (ev2 + 1e-08));

  const bool on = ctr.w > 0.0f;
  const float rx = __fsub_rn(px, ctr.x);
  const float ry = __fsub_rn(py, ctr.y);
  const float rz = __fsub_rn(pz, ctr.z);
  const float dist_c = sqrtf(sq3(rx, ry, rz));
  const float horiz  = sqrtf(__fadd_rn(__fmul_rn(rx, rx), __fmul_rn(ry, ry)));
  const float rad    = atan2f(ry, rx);

  g[0] = on ? dist_c : 0.0f;
  g[1] = on ? rz : 0.0f;
  g[2] = on ? horiz : 0.0f;
  g[3] = on ? dens : 0.0f;
  g[4] = on ? curv : 0.0f;
  g[5] = on ? rad : 0.0f;
}

// ---------------------------------------------------------------------------
// Kernel 0: per-batch masked centroid (deterministic f64 reduce -> f32)
__global__ __launch_bounds__(256) void k_center(const float* __restrict__ points,
                                                const int* __restrict__ mask,
                                                float* __restrict__ centerOut) {
  const int b = blockIdx.x;
  const float* P = points + (size_t)b * N_PTS * 3;
  const int* M = mask + (size_t)b * N_PTS;
  double sx = 0.0, sy = 0.0, sz = 0.0, sc = 0.0;
  for (int i = threadIdx.x; i < N_PTS; i += 256) {
    if (M[i] != 0) {
      sx += (double)P[3 * i + 0];
      sy += (double)P[3 * i + 1];
      sz += (double)P[3 * i + 2];
      sc += 1.0;
    }
  }
  __shared__ double sh[4][256];
  sh[0][threadIdx.x] = sx; sh[1][threadIdx.x] = sy;
  sh[2][threadIdx.x] = sz; sh[3][threadIdx.x] = sc;
  __syncthreads();
  for (int off = 128; off > 0; off >>= 1) {
    if ((int)threadIdx.x < off) {
      sh[0][threadIdx.x] += sh[0][threadIdx.x + off];
      sh[1][threadIdx.x] += sh[1][threadIdx.x + off];
      sh[2][threadIdx.x] += sh[2][threadIdx.x + off];
      sh[3][threadIdx.x] += sh[3][threadIdx.x + off];
    }
    __syncthreads();
  }
  if (threadIdx.x == 0) {
    float cf  = (float)sh[3][0];
    float div = fmaxf(cf, 1.0f);
    centerOut[b * 4 + 0] = (float)sh[0][0] / div;
    centerOut[b * 4 + 1] = (float)sh[1][0] / div;
    centerOut[b * 4 + 2] = (float)sh[2][0] / div;
    centerOut[b * 4 + 3] = (cf > 0.0f) ? 1.0f : 0.0f;   // mask-nonempty flag
  }
}

// ---------------------------------------------------------------------------
// Grid build: count -> scan -> scatter (h = 1/32)
__global__ __launch_bounds__(256) void k_grid_count(const float* __restrict__ points,
                                                    int* __restrict__ count) {
  const int t = blockIdx.x * 256 + threadIdx.x;
  const int b = t >> 13;
  const int i = t & (N_PTS - 1);
  const float* P = points + (size_t)b * N_PTS * 3;
  const int cx = cellOf(P[3 * i + 0]);
  const int cy = cellOf(P[3 * i + 1]);
  const int cz = cellOf(P[3 * i + 2]);
  atomicAdd(&count[b * NCELL + (cz * GDIM + cy) * GDIM + cx], 1);
}

// one block of 1024 threads per batch; exclusive scan of 32768 counts
__global__ __launch_bounds__(1024) void k_scan(const int* __restrict__ count,
                                               int* __restrict__ start,
                                               int* __restrict__ cur) {
  const int b = blockIdx.x;
  const int t = threadIdx.x;
  int c[32]; int sum = 0;
#pragma unroll
  for (int j = 0; j < 32; ++j) { c[j] = count[b * NCELL + t * 32 + j]; sum += c[j]; }
  __shared__ int s[1024];
  s[t] = sum;
  __syncthreads();
  for (int off = 1; off < 1024; off <<= 1) {
    int v = (t >= off) ? s[t - off] : 0;
    __syncthreads();
    if (t >= off) s[t] += v;
    __syncthreads();
  }
  int excl = (t > 0) ? s[t - 1] : 0;
#pragma unroll
  for (int j = 0; j < 32; ++j) {
    start[b * (NCELL + 1) + t * 32 + j] = excl;
    cur[b * NCELL + t * 32 + j] = excl;
    excl += c[j];
  }
  if (t == 1023) start[b * (NCELL + 1) + NCELL] = excl;
}

__global__ __launch_bounds__(256) void k_scatter(const float* __restrict__ points,
                                                 const int* __restrict__ mask,
                                                 int* __restrict__ cur,
                                                 float4* __restrict__ sorted) {
  const int t = blockIdx.x * 256 + threadIdx.x;
  const int b = t >> 13;
  const int i = t & (N_PTS - 1);
  const float* P = points + (size_t)b * N_PTS * 3;
  const float x = P[3 * i + 0], y = P[3 * i + 1], z = P[3 * i + 2];
  const int cell = (cellOf(z) * GDIM + cellOf(y)) * GDIM + cellOf(x);
  const int pos = atomicAdd(&cur[b * NCELL + cell], 1);
  const unsigned wb = (unsigned)i | ((mask[b * N_PTS + i] != 0) ? 0x80000000u : 0u);
  sorted[(size_t)b * N_PTS + pos] = make_float4(x, y, z, __uint_as_float(wb));
}

// ---------------------------------------------------------------------------
// Kernel C: collect-then-sort supercell query. One wave per 6^3-cell supercell.
// Stage +-3-cell halo (C~432) into LDS; each LANE owns one query and scans all
// staged candidates, collecting d2 < COLLECT_T into its private LDS buffer
// (~28 entries); exact (d2,idx)-lex top-11 sort at the end + tie/completeness
// checks flag rare ambiguous queries to the exact fallback.
__global__ __launch_bounds__(64) void k_collect(const float* __restrict__ points,
                                                const float4* __restrict__ sorted,
                                                const int* __restrict__ start,
                                                const float* __restrict__ center,
                                                float* __restrict__ geom,
                                                int* __restrict__ flags,
                                                float COLLECT_T, float DENS_T,
                                                float THR_CHECK) {
  const int b  = blockIdx.y;
  const int sc = blockIdx.x;
  const int sx = sc % NSUP_AX, sy = (sc / NSUP_AX) % NSUP_AX, sz = sc / (NSUP_AX * NSUP_AX);
  const int lane = threadIdx.x;

  const int* ST = start + b * (NCELL + 1);
  const float4* SP = sorted + (size_t)b * N_PTS;

  const int x0 = SUP * sx, x1 = min(SUP * sx + SUP - 1, GDIM - 1);
  const int y0 = SUP * sy, y1 = min(SUP * sy + SUP - 1, GDIM - 1);
  const int z0 = SUP * sz, z1 = min(SUP * sz + SUP - 1, GDIM - 1);
  if (x0 > GDIM - 1 || y0 > GDIM - 1 || z0 > GDIM - 1) return;
  const int hx0 = max(x0 - 3, 0), hx1 = min(x1 + 3, GDIM - 1);
  const int hy0 = max(y0 - 3, 0), hy1 = min(y1 + 3, GDIM - 1);
  const int hz0 = max(z0 - 3, 0), hz1 = min(z1 + 3, GDIM - 1);
  const int yc = hy1 - hy0 + 1;
  const int R  = (hz1 - hz0 + 1) * yc;

  __shared__ int   rs[MAXROWS], rp[MAXROWS + 1];
  __shared__ int   qs_[36], qp_[37];
  __shared__ float4 pts4[SCAP];
  __shared__ u64   lbuf[64 * BUF_CAP];

  // ---- query rows (<=36) prefix ----
  const int qyc = y1 - y0 + 1;
  const int qR  = (z1 - z0 + 1) * qyc;
  {
    int ql[3] = {0, 0, 0}, qsr[3] = {0, 0, 0};
#pragma unroll
    for (int k = 0; k < 3; ++k) {
      const int r = 3 * lane + k;
      if (r < qR) {
        const int z = z0 + r / qyc, y = y0 + r % qyc;
        const int base = (z * GDIM + y) * GDIM;
        qsr[k] = ST[base + x0];
        ql[k]  = ST[base + x1 + 1] - qsr[k];
      }
    }
    int qsum = ql[0] + ql[1] + ql[2];
    int qinc = qsum;
    for (int off = 1; off < 64; off <<= 1) {
      int v = __shfl_up(qinc, off);
      if (lane >= off) qinc += v;
    }
    const int qtot_ = __shfl(qinc, 63);
    int qexc = qinc - qsum;
#pragma unroll
    for (int k = 0; k < 3; ++k) {
      const int r = 3 * lane + k;
      if (r < qR) { qs_[r] = qsr[k]; qp_[r] = qexc; }
      qexc += ql[k];
    }
    if (lane == 0) qp_[qR] = qtot_;
  }
  __syncthreads();
  const int qtot = qp_[qR];
  if (qtot == 0) return;

  // ---- halo rows (<=144) prefix ----
  int C;
  {
    int l[3] = {0, 0, 0}, sr[3] = {0, 0, 0};
#pragma unroll
    for (int k = 0; k < 3; ++k) {
      const int r = 3 * lane + k;
      if (r < R) {
        const int z = hz0 + r / yc, y = hy0 + r % yc;
        const int base = (z * GDIM + y) * GDIM;
        sr[k] = ST[base + hx0];
        l[k]  = ST[base + hx1 + 1] - sr[k];
      }
    }
    int msum = l[0] + l[1] + l[2];
    int minc = msum;
    for (int off = 1; off < 64; off <<= 1) {
      int v = __shfl_up(minc, off);
      if (lane >= off) minc += v;
    }
    C = __shfl(minc, 63);
    int mexc = minc - msum;
#pragma unroll
    for (int k = 0; k < 3; ++k) {
      const int r = 3 * lane + k;
      if (r < R) { rs[r] = sr[k]; rp[r] = mexc; }
      mexc += l[k];
    }
    if (lane == 0) rp[R] = C;
  }
  __syncthreads();

  const float4 ctr = reinterpret_cast<const float4*>(center)[b];
  const float* P = points + (size_t)b * N_PTS * 3;

  if (C > SCAP) {                 // astronomically rare: everything to fallback
    for (int q0 = 0; q0 < qtot; q0 += 64) {
      const int myq = q0 + lane;
      if (myq < qtot) {
        int lo = 0, hi = qR - 1;
        while (lo < hi) { const int mid = (lo + hi + 1) >> 1; if (qp_[mid] <= myq) lo = mid; else hi = mid - 1; }
        flags[b * N_PTS + (qs_[lo] + (myq - qp_[lo]))] = 1;
      }
    }
    return;
  }

  // ---- stage halo ----
  for (int i = lane; i < C; i += 64) {
    int lo = 0, hi = R - 1;
    while (lo < hi) { const int mid = (lo + hi + 1) >> 1; if (rp[mid] <= i) lo = mid; else hi = mid - 1; }
    pts4[i] = SP[rs[lo] + (i - rp[lo])];
  }
  __syncthreads();

  // ---- one query per lane ----
  for (int q0 = 0; q0 < qtot; q0 += 64) {
    const int myq = q0 + lane;
    const bool act = (myq < qtot);
    const int mq = act ? myq : 0;
    int lo = 0, hi = qR - 1;
    while (lo < hi) { const int mid = (lo + hi + 1) >> 1; if (qp_[mid] <= mq) lo = mid; else hi = mid - 1; }
    const int qglob = qs_[lo] + (mq - qp_[lo]);
    const float4 qp4 = SP[qglob];
    const unsigned qw = __float_as_uint(qp4.w);
    const int qidx = (int)(qw & 0x7FFFFFFFu);
    const float px = qp4.x, py = qp4.y, pz = qp4.z;
    const float sqq = sq3(px, py, pz);

    int cnt = 0;
    for (int j = 0; j < C; ++j) {
      const float4 tp = pts4[j];                      // LDS broadcast
      const float sqc = sq3(tp.x, tp.y, tp.z);
      const float dot = __fmaf_rn(pz, tp.z, __fmaf_rn(py, tp.y, __fmul_rn(px, tp.x)));
      const float d2  = __fsub_rn(__fadd_rn(sqq, sqc), __fmul_rn(2.0f, dot));
      const float d2c = fmaxf(d2, 0.0f);
      if (d2c < COLLECT_T) {
        if (cnt < BUF_CAP) {
          const unsigned wb = __float_as_uint(tp.w);
          lbuf[lane * BUF_CAP + cnt] = ((u64)__float_as_uint(d2c) << 32)
                                     | (u64)(((wb & 0x7FFFFFFFu) << 1) | (wb >> 31));
        }
        ++cnt;
      }
    }

    // ---- finalize: exact (d2,idx)-lex top-11 over collected + density ----
    u64 best[11];
#pragma unroll
    for (int j = 0; j < 11; ++j) best[j] = ~0ull;
    float dens = 0.0f;
    const int m = min(cnt, BUF_CAP);
    for (int i = 0; i < m; ++i) {
      const u64 e = lbuf[lane * BUF_CAP + i];
      const float d2v = __uint_as_float((unsigned)(e >> 32));
      if ((e & 1ull) && d2v < DENS_T) dens += 1.0f;
      if (e < best[10]) insert11(best, e);
    }
    bool bad = (cnt < 10) || (cnt > BUF_CAP);
    const float dist9 = sqrtf(__uint_as_float((unsigned)(best[9] >> 32)));
    bad = bad || !(dist9 < THR_CHECK);
    if (cnt >= 11) {
      const float dist10 = sqrtf(__uint_as_float((unsigned)(best[10] >> 32)));
      bad = bad || (dist10 == dist9);
    }

    if (act) {
      if (bad) {
        flags[b * N_PTS + qglob] = 1;
      } else {
        flags[b * N_PTS + qglob] = 0;
        int idxs[10];
#pragma unroll
        for (int j = 0; j < 10; ++j) idxs[j] = (int)(((unsigned)best[j]) >> 1);
        geom_epilogue(P, idxs, dens, px, py, pz, ctr,
                      geom + ((size_t)b * N_PTS + qidx) * 6);
      }
    }
  }
}

// ---------------------------------------------------------------------------
// Fallback: exact (dist,idx) ring-scan, gated on flag (runs for ~1 query)
__global__ __launch_bounds__(256) void k_fallback(const float* __restrict__ points,
                                                  const float4* __restrict__ sorted,
                                                  const int* __restrict__ start,
                                                  const float* __restrict__ center,
                                                  float* __restrict__ geom,
                                                  const int* __restrict__ flags) {
  const int b = blockIdx.y;
  const int qs = blockIdx.x * 256 + threadIdx.x;
  if (flags[b * N_PTS + qs] == 0) return;
  const float4 qp = sorted[(size_t)b * N_PTS + qs];
  const unsigned qw = __float_as_uint(qp.w);
  const int qidx = (int)(qw & 0x7FFFFFFFu);

  const float px = qp.x, py = qp.y, pz = qp.z;
  const float sqq = sq3(px, py, pz);
  const int cx = cellOf(px), cy = cellOf(py), cz = cellOf(pz);

  const int* ST = start + b * (NCELL + 1);
  const float4* SP = sorted + (size_t)b * N_PTS;

  u64 best[10];
#pragma unroll
  for (int j = 0; j < 10; ++j) best[j] = ((u64)0x7F800000u << 32) | 0xFFFFFFFFu;
  float dens = 0.0f;

  for (int rho = 0; rho < GDIM; ++rho) {
    const int zlo = max(cz - rho, 0), zhi = min(cz + rho, GDIM - 1);
    const int ylo = max(cy - rho, 0), yhi = min(cy + rho, GDIM - 1);
    for (int z = zlo; z <= zhi; ++z) {
      const int adz = abs(z - cz);
      for (int y = ylo; y <= yhi; ++y) {
        const int ady = abs(y - cy);
        const int m2 = max(adz, ady);
        int ja, jb;
        int ja2 = 0, jb2 = 0;
        const int rowBase = (z * GDIM + y) * GDIM;
        if (m2 == rho) {
          const int xa = max(cx - rho, 0), xb = min(cx + rho, GDIM - 1);
          ja = ST[rowBase + xa]; jb = ST[rowBase + xb + 1];
        } else {
          ja = jb = 0;
          if (cx - rho >= 0)        { ja = ST[rowBase + cx - rho]; jb = ST[rowBase + cx - rho + 1]; }
          if (cx + rho <= GDIM - 1) { ja2 = ST[rowBase + cx + rho]; jb2 = ST[rowBase + cx + rho + 1]; }
        }
#pragma unroll 1
        for (int pass = 0; pass < 2; ++pass) {
          const int j0 = pass ? ja2 : ja;
          const int j1 = pass ? jb2 : jb;
          for (int j = j0; j < j1; ++j) {
            const float4 tp = SP[j];
            const unsigned wb = __float_as_uint(tp.w);
            const float sqc = sq3(tp.x, tp.y, tp.z);
            const float dot = __fmaf_rn(pz, tp.z, __fmaf_rn(py, tp.y, __fmul_rn(px, tp.x)));
            const float d2  = __fsub_rn(__fadd_rn(sqq, sqc), __fmul_rn(2.0f, dot));
            const float dist = sqrtf(fmaxf(d2, 0.0f));
            if ((dist < RADIUS_F) && (wb & 0x80000000u)) dens += 1.0f;
            const u64 key = ((u64)__float_as_uint(dist) << 32) | (wb & 0x7FFFFFFFu);
            if (key < best[9]) insert10(best, key);
          }
        }
      }
    }
    if (rho >= 1) {
      const float dist9 = __uint_as_float((unsigned)(best[9] >> 32));
      if (dist9 < (float)rho * HCELL * 0.999f) break;
    }
  }

  const float4 ctr = reinterpret_cast<const float4*>(center)[b];
  const float* P = points + (size_t)b * N_PTS * 3;
  int idxs[10];
#pragma unroll
  for (int j = 0; j < 10; ++j) idxs[j] = (int)(((unsigned)best[j]) & 0x7FFFFFFFu);
  geom_epilogue(P, idxs, dens, px, py, pz, ctr, geom + ((size_t)b * N_PTS + qidx) * 6);
}

// ---------------------------------------------------------------------------
// Kernel 3: fused 2-layer MLP (unchanged).
__global__ __launch_bounds__(256) void k_mlp(const float* __restrict__ features,
                                             const float* __restrict__ geom,
                                             const float* __restrict__ W1,
                                             const float* __restrict__ b1,
                                             const float* __restrict__ W2,
                                             const float* __restrict__ b2,
                                             float* __restrict__ out) {
  __shared__ float A[64][74];
  __shared__ float H[64][130];
  const int tid = threadIdx.x;
  const int row0 = blockIdx.x * 64;

  for (int i = tid; i < 64 * IN_DIM; i += 256) {
    int r = i >> 6, k = i & 63;
    A[r][k] = features[(size_t)(row0 + r) * IN_DIM + k];
  }
  for (int i = tid; i < 64 * 8; i += 256) {
    int r = i >> 3, k = i & 7;
    if (k < 6) A[r][IN_DIM + k] = geom[(size_t)(row0 + r) * 6 + k];
  }
  __syncthreads();

  const int ty = tid >> 4;
  const int tx = tid & 15;

  float acc[4][8];
#pragma unroll
  for (int i = 0; i < 4; ++i)
#pragma unroll
    for (int j = 0; j < 8; ++j) acc[i][j] = 0.0f;

#pragma unroll 2
  for (int k = 0; k < D_IN; ++k) {
    float a[4];
#pragma unroll
    for (int i = 0; i < 4; ++i) a[i] = A[ty * 4 + i][k];
    float4 w0 = *reinterpret_cast<const float4*>(&W1[(size_t)k * ODIM + tx * 8]);
    float4 w1 = *reinterpret_cast<const float4*>(&W1[(size_t)k * ODIM + tx * 8 + 4]);
    float w[8] = {w0.x, w0.y, w0.z, w0.w, w1.x, w1.y, w1.z, w1.w};
#pragma unroll
    for (int i = 0; i < 4; ++i)
#pragma unroll
      for (int j = 0; j < 8; ++j) acc[i][j] = fmaf(a[i], w[j], acc[i][j]);
  }

  {
    float4 bb0 = *reinterpret_cast<const float4*>(&b1[tx * 8]);
    float4 bb1 = *reinterpret_cast<const float4*>(&b1[tx * 8 + 4]);
    float bb[8] = {bb0.x, bb0.y, bb0.z, bb0.w, bb1.x, bb1.y, bb1.z, bb1.w};
#pragma unroll
    for (int i = 0; i < 4; ++i) {
      float4 h0 = make_float4(fmaxf(acc[i][0] + bb[0], 0.f), fmaxf(acc[i][1] + bb[1], 0.f),
                              fmaxf(acc[i][2] + bb[2], 0.f), fmaxf(acc[i][3] + bb[3], 0.f));
      float4 h1 = make_float4(fmaxf(acc[i][4] + bb[4], 0.f), fmaxf(acc[i][5] + bb[5], 0.f),
                              fmaxf(acc[i][6] + bb[6], 0.f), fmaxf(acc[i][7] + bb[7], 0.f));
      *reinterpret_cast<float4*>(&H[ty * 4 + i][tx * 8]) = h0;
      *reinterpret_cast<float4*>(&H[ty * 4 + i][tx * 8 + 4]) = h1;
    }
  }
  __syncthreads();

#pragma unroll
  for (int i = 0; i < 4; ++i)
#pragma unroll
    for (int j = 0; j < 8; ++j) acc[i][j] = 0.0f;

#pragma unroll 2
  for (int k = 0; k < ODIM; ++k) {
    float a[4];
#pragma unroll
    for (int i = 0; i < 4; ++i) a[i] = H[ty * 4 + i][k];
    float4 w0 = *reinterpret_cast<const float4*>(&W2[(size_t)k * ODIM + tx * 8]);
    float4 w1 = *reinterpret_cast<const float4*>(&W2[(size_t)k * ODIM + tx * 8 + 4]);
    float w[8] = {w0.x, w0.y, w0.z, w0.w, w1.x, w1.y, w1.z, w1.w};
#pragma unroll
    for (int i = 0; i < 4; ++i)
#pragma unroll
      for (int j = 0; j < 8; ++j) acc[i][j] = fmaf(a[i], w[j], acc[i][j]);
  }

  {
    float4 bb0 = *reinterpret_cast<const float4*>(&b2[tx * 8]);
    float4 bb1 = *reinterpret_cast<const float4*>(&b2[tx * 8 + 4]);
    float bb[8] = {bb0.x, bb0.y, bb0.z, bb0.w, bb1.x, bb1.y, bb1.z, bb1.w};
#pragma unroll
    for (int i = 0; i < 4; ++i) {
      size_t row = (size_t)(row0 + ty * 4 + i);
      float4 o0 = make_float4(fmaxf(acc[i][0] + bb[0], 0.f), fmaxf(acc[i][1] + bb[1], 0.f),
                              fmaxf(acc[i][2] + bb[2], 0.f), fmaxf(acc[i][3] + bb[3], 0.f));
      float4 o1 = make_float4(fmaxf(acc[i][4] + bb[4], 0.f), fmaxf(acc[i][5] + bb[5], 0.f),
                              fmaxf(acc[i][6] + bb[6], 0.f), fmaxf(acc[i][7] + bb[7], 0.f));
      *reinterpret_cast<float4*>(&out[row * ODIM + tx * 8]) = o0;
      *reinterpret_cast<float4*>(&out[row * ODIM + tx * 8 + 4]) = o1;
    }
  }
}

// ---------------------------------------------------------------------------
extern "C" void kernel_launch(void* const* d_in, const int* in_sizes, int n_in,
                              void* d_out, int out_size, void* d_ws, size_t ws_size,
                              hipStream_t stream) {
  const float* points   = (const float*)d_in[0];
  const float* features = (const float*)d_in[1];
  const int*   mask     = (const int*)d_in[2];
  const float* W1       = (const float*)d_in[3];
  const float* b1       = (const float*)d_in[4];
  const float* W2       = (const float*)d_in[5];
  const float* b2       = (const float*)d_in[6];
  float* out = (float*)d_out;

  // exact density threshold: dist < R  <=>  d2c < DENS_T  (d2c, dist f32; RN sqrt)
  const double Rd   = (double)0.02f;
  const double midd = Rd - ldexp(1.0, -30);     // halfway(pred(R), R)
  const double Td   = midd * midd;
  float densT = (float)Td;
  if ((double)densT <= Td) densT = nextafterf(densT, 1.0f);
  const float collectT = 0.0935f * 0.0935f;     // collect radius^2 (< (3h)^2 with margin)
  const float thrCheck = 0.0934f;               // completeness check on dist9

  // ws layout (all 256B aligned):
  char* w = (char*)d_ws;
  size_t off = 0;
  auto take = [&](size_t bytes) { char* p = w + off; off = (off + bytes + 255) & ~(size_t)255; return p; };
  float*  geomBuf   = (float*)take((size_t)NQ_ALL * 6 * 4);
  float*  centerBuf = (float*)take(2 * 16);
  int*    countBuf  = (int*)take((size_t)B_SZ * NCELL * 4);
  int*    startBuf  = (int*)take((size_t)B_SZ * (NCELL + 1) * 4);
  int*    curBuf    = (int*)take((size_t)B_SZ * NCELL * 4);
  float4* sortedBuf = (float4*)take((size_t)B_SZ * N_PTS * 16);
  int*    flagsBuf  = (int*)take((size_t)NQ_ALL * 4);
  (void)ws_size;

  hipMemsetAsync(countBuf, 0, (size_t)B_SZ * NCELL * 4, stream);
  k_center<<<B_SZ, 256, 0, stream>>>(points, mask, centerBuf);
  k_grid_count<<<NQ_ALL / 256, 256, 0, stream>>>(points, countBuf);
  k_scan<<<B_SZ, 1024, 0, stream>>>(countBuf, startBuf, curBuf);
  k_scatter<<<NQ_ALL / 256, 256, 0, stream>>>(points, mask, curBuf, sortedBuf);
  k_collect<<<dim3(NSUPER, B_SZ), 64, 0, stream>>>(points, sortedBuf, startBuf, centerBuf,
                                                   geomBuf, flagsBuf, collectT, densT, thrCheck);
  k_fallback<<<dim3(N_PTS / 256, B_SZ), 256, 0, stream>>>(points, sortedBuf, startBuf,
                                                          centerBuf, geomBuf, flagsBuf);
  k_mlp<<<NQ_ALL / 64, 256, 0, stream>>>(features, geomBuf, W1, b1, W2, b2, out);
}

// Round 5
// 227.211 us; speedup vs baseline: 1.6480x; 1.6480x over previous
//
#include <hip/hip_runtime.h>
#include <math.h>
#include <stdint.h>

#define B_SZ   2
#define N_PTS  8192
#define IN_DIM 64
#define D_IN   70          // 64 features + 6 geom
#define ODIM   128
#define NQ_ALL (B_SZ * N_PTS)
#define RADIUS_F 0.02f

#define GDIM  32
#define NCELL (GDIM * GDIM * GDIM)
#define HCELL 0.03125f     // 1/32, exact in f32

#define SUP     4                       // base cells per supercell axis (exact tiling)
#define NSUP_AX 8
#define NSUPER  (NSUP_AX * NSUP_AX * NSUP_AX)   // 512
#define SCAP    352                     // staged halo capacity (lambda 250 + 6 sigma)
#define LCAP    24                      // per-lane collect buffer (lambda 7)
#define MAXROWS 100                     // 10x10 halo (z,y) rows max

typedef unsigned long long u64;

// ---------------------------------------------------------------------------
__device__ __forceinline__ void insert11(u64 (&best)[11], u64 key) {
#pragma unroll
  for (int j = 10; j >= 1; --j) {
    u64 hi = (best[j - 1] > key) ? best[j - 1] : key;
    best[j] = (best[j] < hi) ? best[j] : hi;
  }
  best[0] = (best[0] < key) ? best[0] : key;
}
__device__ __forceinline__ void insert10(u64 (&best)[10], u64 key) {
#pragma unroll
  for (int j = 9; j >= 1; --j) {
    u64 hi = (best[j - 1] > key) ? best[j - 1] : key;
    best[j] = (best[j] < hi) ? best[j] : hi;
  }
  best[0] = (best[0] < key) ? best[0] : key;
}

// exact f32 helpers matching the reference's op order (no contraction)
__device__ __forceinline__ float sq3(float x, float y, float z) {
  return __fadd_rn(__fadd_rn(__fmul_rn(x, x), __fmul_rn(y, y)), __fmul_rn(z, z));
}

__device__ __forceinline__ int cellOf(float v) {
  int c = (int)(v * 32.0f);            // v*32 is exact (power-of-2 scale)
  return min(max(c, 0), GDIM - 1);
}

// shared epilogue: covariance over the 10 NN (exact f64) + eigen + geometry
__device__ __forceinline__ void geom_epilogue(const float* __restrict__ P,
                                              const int (&idxs)[10], float dens,
                                              float px, float py, float pz,
                                              float4 ctr, float* __restrict__ g) {
  double c00 = 0, c01 = 0, c02 = 0, c11 = 0, c12 = 0, c22 = 0;
#pragma unroll
  for (int j = 0; j < 10; ++j) {
    const int idx = idxs[j];
    const float nx = P[3 * idx + 0], ny = P[3 * idx + 1], nz = P[3 * idx + 2];
    const float ex = __fsub_rn(nx, px);
    const float ey = __fsub_rn(ny, py);
    const float ez = __fsub_rn(nz, pz);
    c00 += (double)ex * ex; c01 += (double)ex * ey; c02 += (double)ex * ez;
    c11 += (double)ey * ey; c12 += (double)ey * ez; c22 += (double)ez * ez;
  }
  const double a00 = c00 / 10.0, a01 = c01 / 10.0, a02 = c02 / 10.0;
  const double a11 = c11 / 10.0, a12 = c12 / 10.0, a22 = c22 / 10.0;

  double p1 = a01 * a01 + a02 * a02 + a12 * a12;
  double qq = (a00 + a11 + a22) / 3.0;
  double p2 = (a00 - qq) * (a00 - qq) + (a11 - qq) * (a11 - qq) +
              (a22 - qq) * (a22 - qq) + 2.0 * p1;
  double ev0, ev2;
  if (p2 <= 1e-60) {
    ev0 = ev2 = qq;
  } else {
    double p = sqrt(p2 / 6.0);
    double invp = 1.0 / p;
    double b00 = (a00 - qq) * invp, b11 = (a11 - qq) * invp, b22 = (a22 - qq) * invp;
    double b01 = a01 * invp, b02 = a02 * invp, b12 = a12 * invp;
    double detB = b00 * (b11 * b22 - b12 * b12) - b01 * (b01 * b22 - b12 * b02) +
                  b02 * (b01 * b12 - b11 * b02);
    double r = 0.5 * detB;
    r = fmin(1.0, fmax(-1.0, r));
    double phi = acos(r) / 3.0;
    ev2 = qq + 2.0 * p * cos(phi);
    ev0 = qq + 2.0 * p * cos(phi + 2.0943951023931953);  // +2*pi/3
  }
  const float curv = (float)(ev0 / (ev2 + 1e-08));

  const bool on = ctr.w > 0.0f;
  const float rx = __fsub_rn(px, ctr.x);
  const float ry = __fsub_rn(py, ctr.y);
  const float rz = __fsub_rn(pz, ctr.z);
  const float dist_c = sqrtf(sq3(rx, ry, rz));
  const float horiz  = sqrtf(__fadd_rn(__fmul_rn(rx, rx), __fmul_rn(ry, ry)));
  const float rad    = atan2f(ry, rx);

  g[0] = on ? dist_c : 0.0f;
  g[1] = on ? rz : 0.0f;
  g[2] = on ? horiz : 0.0f;
  g[3] = on ? dens : 0.0f;
  g[4] = on ? curv : 0.0f;
  g[5] = on ? rad : 0.0f;
}

// ---------------------------------------------------------------------------
// Kernel 0: per-batch masked centroid (deterministic f64 reduce -> f32)
__global__ __launch_bounds__(256) void k_center(const float* __restrict__ points,
                                                const int* __restrict__ mask,
                                                float* __restrict__ centerOut) {
  const int b = blockIdx.x;
  const float* P = points + (size_t)b * N_PTS * 3;
  const int* M = mask + (size_t)b * N_PTS;
  double sx = 0.0, sy = 0.0, sz = 0.0, sc = 0.0;
  for (int i = threadIdx.x; i < N_PTS; i += 256) {
    if (M[i] != 0) {
      sx += (double)P[3 * i + 0];
      sy += (double)P[3 * i + 1];
      sz += (double)P[3 * i + 2];
      sc += 1.0;
    }
  }
  __shared__ double sh[4][256];
  sh[0][threadIdx.x] = sx; sh[1][threadIdx.x] = sy;
  sh[2][threadIdx.x] = sz; sh[3][threadIdx.x] = sc;
  __syncthreads();
  for (int off = 128; off > 0; off >>= 1) {
    if ((int)threadIdx.x < off) {
      sh[0][threadIdx.x] += sh[0][threadIdx.x + off];
      sh[1][threadIdx.x] += sh[1][threadIdx.x + off];
      sh[2][threadIdx.x] += sh[2][threadIdx.x + off];
      sh[3][threadIdx.x] += sh[3][threadIdx.x + off];
    }
    __syncthreads();
  }
  if (threadIdx.x == 0) {
    float cf  = (float)sh[3][0];
    float div = fmaxf(cf, 1.0f);
    centerOut[b * 4 + 0] = (float)sh[0][0] / div;
    centerOut[b * 4 + 1] = (float)sh[1][0] / div;
    centerOut[b * 4 + 2] = (float)sh[2][0] / div;
    centerOut[b * 4 + 3] = (cf > 0.0f) ? 1.0f : 0.0f;   // mask-nonempty flag
  }
}

// ---------------------------------------------------------------------------
// Grid build: count -> scan -> scatter (h = 1/32)
__global__ __launch_bounds__(256) void k_grid_count(const float* __restrict__ points,
                                                    int* __restrict__ count) {
  const int t = blockIdx.x * 256 + threadIdx.x;
  const int b = t >> 13;
  const int i = t & (N_PTS - 1);
  const float* P = points + (size_t)b * N_PTS * 3;
  const int cx = cellOf(P[3 * i + 0]);
  const int cy = cellOf(P[3 * i + 1]);
  const int cz = cellOf(P[3 * i + 2]);
  atomicAdd(&count[b * NCELL + (cz * GDIM + cy) * GDIM + cx], 1);
}

// one block of 1024 threads per batch; exclusive scan of 32768 counts
__global__ __launch_bounds__(1024) void k_scan(const int* __restrict__ count,
                                               int* __restrict__ start,
                                               int* __restrict__ cur) {
  const int b = blockIdx.x;
  const int t = threadIdx.x;
  int c[32]; int sum = 0;
#pragma unroll
  for (int j = 0; j < 32; ++j) { c[j] = count[b * NCELL + t * 32 + j]; sum += c[j]; }
  __shared__ int s[1024];
  s[t] = sum;
  __syncthreads();
  for (int off = 1; off < 1024; off <<= 1) {
    int v = (t >= off) ? s[t - off] : 0;
    __syncthreads();
    if (t >= off) s[t] += v;
    __syncthreads();
  }
  int excl = (t > 0) ? s[t - 1] : 0;
#pragma unroll
  for (int j = 0; j < 32; ++j) {
    start[b * (NCELL + 1) + t * 32 + j] = excl;
    cur[b * NCELL + t * 32 + j] = excl;
    excl += c[j];
  }
  if (t == 1023) start[b * (NCELL + 1) + NCELL] = excl;
}

__global__ __launch_bounds__(256) void k_scatter(const float* __restrict__ points,
                                                 const int* __restrict__ mask,
                                                 int* __restrict__ cur,
                                                 float4* __restrict__ sorted) {
  const int t = blockIdx.x * 256 + threadIdx.x;
  const int b = t >> 13;
  const int i = t & (N_PTS - 1);
  const float* P = points + (size_t)b * N_PTS * 3;
  const float x = P[3 * i + 0], y = P[3 * i + 1], z = P[3 * i + 2];
  const int cell = (cellOf(z) * GDIM + cellOf(y)) * GDIM + cellOf(x);
  const int pos = atomicAdd(&cur[b * NCELL + cell], 1);
  const unsigned wb = (unsigned)i | ((mask[b * N_PTS + i] != 0) ? 0x80000000u : 0u);
  sorted[(size_t)b * N_PTS + pos] = make_float4(x, y, z, __uint_as_float(wb));
}

// ---------------------------------------------------------------------------
// Kernel C: collect-then-sort. One wave per 4^3-cell supercell (exact 8^3
// tiling), +-3-cell halo staged to LDS (C~250). 4 lanes per query, each lane
// scans a stride-4 partition collecting d2 < COLLECT_T into a 24-entry LDS
// buffer; per-lane (d2,idx)-lex sort + 2-step group merge; completeness/tie
// checks append ambiguous queries to the tier-2 list.
__global__ __launch_bounds__(64) void k_collect(const float* __restrict__ points,
                                                const float4* __restrict__ sorted,
                                                const int* __restrict__ start,
                                                const float* __restrict__ center,
                                                float* __restrict__ geom,
                                                int* __restrict__ list,
                                                int* __restrict__ listCnt,
                                                float COLLECT_T, float DENS_T,
                                                float THR_CHECK) {
  const int b  = blockIdx.y;
  const int sc = blockIdx.x;
  const int sx = sc & 7, sy = (sc >> 3) & 7, sz = sc >> 6;
  const int lane = threadIdx.x;

  const int* ST = start + b * (NCELL + 1);
  const float4* SP = sorted + (size_t)b * N_PTS;

  const int x0 = SUP * sx, x1 = SUP * sx + SUP - 1;
  const int y0 = SUP * sy, y1 = SUP * sy + SUP - 1;
  const int z0 = SUP * sz, z1 = SUP * sz + SUP - 1;
  const int hx0 = max(x0 - 3, 0), hx1 = min(x1 + 3, GDIM - 1);
  const int hy0 = max(y0 - 3, 0), hy1 = min(y1 + 3, GDIM - 1);
  const int hz0 = max(z0 - 3, 0), hz1 = min(z1 + 3, GDIM - 1);
  const int yc = hy1 - hy0 + 1;               // <=10
  const int R  = (hz1 - hz0 + 1) * yc;        // <=100

  __shared__ int    rs[MAXROWS], rp[MAXROWS + 1];
  __shared__ int    qs_[16], qp_[17];
  __shared__ float4 pts4[SCAP];
  __shared__ u64    lbuf[64 * LCAP];

  // query rows: exactly 16 (4 z x 4 y); lane<16 owns row `lane`
  {
    int qlen = 0, qst = 0;
    if (lane < 16) {
      const int z = z0 + (lane >> 2), y = y0 + (lane & 3);
      const int base = (z * GDIM + y) * GDIM;
      qst  = ST[base + x0];
      qlen = ST[base + x1 + 1] - qst;
    }
    int inc = qlen;
    for (int off = 1; off < 64; off <<= 1) { int v = __shfl_up(inc, off); if (lane >= off) inc += v; }
    if (lane < 16) { qs_[lane] = qst; qp_[lane] = inc - qlen; }
    if (lane == 63) qp_[16] = inc;
  }
  // halo rows: 2 per lane, in row order
  {
    int len[2] = {0, 0}, st2[2] = {0, 0};
#pragma unroll
    for (int k = 0; k < 2; ++k) {
      const int r = lane * 2 + k;
      if (r < R) {
        const int z = hz0 + r / yc, y = hy0 + r % yc;
        const int base = (z * GDIM + y) * GDIM;
        st2[k] = ST[base + hx0];
        len[k] = ST[base + hx1 + 1] - st2[k];
      }
    }
    int sum = len[0] + len[1];
    int inc = sum;
    for (int off = 1; off < 64; off <<= 1) { int v = __shfl_up(inc, off); if (lane >= off) inc += v; }
    int exc = inc - sum;
#pragma unroll
    for (int k = 0; k < 2; ++k) {
      const int r = lane * 2 + k;
      if (r < R) { rs[r] = st2[k]; rp[r] = exc; }
      exc += len[k];
    }
    if (lane == 63) rp[R] = inc;
  }
  __syncthreads();

  const int C    = rp[R];
  const int qtot = qp_[16];
  if (qtot == 0) return;

  if (C > SCAP) {                 // astronomically rare: all queries to tier-2
    for (int t = lane; t < qtot; t += 64) {
      int lo = 0, hi = 15;
      while (lo < hi) { const int mid = (lo + hi + 1) >> 1; if (qp_[mid] <= t) lo = mid; else hi = mid - 1; }
      const int qglob = qs_[lo] + (t - qp_[lo]);
      const int pos = atomicAdd(listCnt, 1);
      list[pos] = (b << 13) | qglob;
    }
    return;
  }

  for (int i = lane; i < C; i += 64) {   // stage halo
    int lo = 0, hi = R - 1;
    while (lo < hi) { const int mid = (lo + hi + 1) >> 1; if (rp[mid] <= i) lo = mid; else hi = mid - 1; }
    pts4[i] = SP[rs[lo] + (i - rp[lo])];
  }
  __syncthreads();

  const float4 ctr = reinterpret_cast<const float4*>(center)[b];
  const float* P = points + (size_t)b * N_PTS * 3;
  const int sub = lane & 3;     // 4 lanes per query
  const int gq  = lane >> 2;    // 16 queries per pass

  for (int q0 = 0; q0 < qtot; q0 += 16) {
    const int myq = q0 + gq;
    const bool act = (myq < qtot);
    const int mq = act ? myq : 0;
    int lo = 0, hi = 15;
    while (lo < hi) { const int mid = (lo + hi + 1) >> 1; if (qp_[mid] <= mq) lo = mid; else hi = mid - 1; }
    const int qglob = qs_[lo] + (mq - qp_[lo]);
    const float4 qp4 = SP[qglob];
    const int qidx = (int)(__float_as_uint(qp4.w) & 0x7FFFFFFFu);
    const float px = qp4.x, py = qp4.y, pz = qp4.z;
    const float sqq = sq3(px, py, pz);

    int cnt = 0;
    u64* myb = &lbuf[lane * LCAP];
    for (int j = sub; j < C; j += 4) {
      const float4 tp = pts4[j];                      // 4-address broadcast, conflict-free
      const float sqc = sq3(tp.x, tp.y, tp.z);
      const float dot = __fmaf_rn(pz, tp.z, __fmaf_rn(py, tp.y, __fmul_rn(px, tp.x)));
      const float d2  = __fsub_rn(__fadd_rn(sqq, sqc), __fmul_rn(2.0f, dot));
      const float d2c = fmaxf(d2, 0.0f);
      if (d2c < COLLECT_T) {
        if (cnt < LCAP) {
          const unsigned wb = __float_as_uint(tp.w);
          myb[cnt] = ((u64)__float_as_uint(d2c) << 32)
                   | (u64)(((wb & 0x7FFFFFFFu) << 1) | (wb >> 31));
        }
        ++cnt;
      }
    }

    // per-lane finalize from buffer
    u64 best[11];
#pragma unroll
    for (int j = 0; j < 11; ++j) best[j] = ~0ull;
    float dens = 0.0f;
    const int m = min(cnt, LCAP);
    for (int i = 0; i < m; ++i) {
      const u64 e = myb[i];
      if ((e & 1ull) && __uint_as_float((unsigned)(e >> 32)) < DENS_T) dens += 1.0f;
      if (e < best[10]) insert11(best, e);
    }
    int cntg = cnt;
    int over = (cnt > LCAP) ? 1 : 0;
    // 2-step butterfly merge within the 4-lane group
#pragma unroll
    for (int s = 1; s < 4; s <<= 1) {
      dens += __shfl_xor(dens, s);
      cntg += __shfl_xor(cntg, s);
      over |= __shfl_xor(over, s);
      u64 ok[11];
#pragma unroll
      for (int j = 0; j < 11; ++j) ok[j] = __shfl_xor(best[j], s);
#pragma unroll
      for (int j = 0; j < 11; ++j) {
        if (ok[j] < best[10]) insert11(best, ok[j]); else break;
      }
    }

    if (act && sub == 0) {
      const float dist9 = sqrtf(__uint_as_float((unsigned)(best[9] >> 32)));
      bool bad = (over != 0) || (cntg < 10) || !(dist9 < THR_CHECK);
      if (cntg >= 11) {
        const float dist10 = sqrtf(__uint_as_float((unsigned)(best[10] >> 32)));
        bad = bad || (dist10 == dist9);
      }
      if (bad) {
        const int pos = atomicAdd(listCnt, 1);
        list[pos] = (b << 13) | qglob;
      } else {
        int idxs[10];
#pragma unroll
        for (int j = 0; j < 10; ++j) idxs[j] = (int)(((unsigned)best[j]) >> 1);
        geom_epilogue(P, idxs, dens, px, py, pz, ctr,
                      geom + ((size_t)b * N_PTS + qidx) * 6);
      }
    }
  }
}

// ---------------------------------------------------------------------------
// Tier-2: one wave per flagged query (grid-stride over compacted list).
// Scans the +-8-cell window (coverage radius > 0.25 exactly; cell assignment
// is exact) with lanes partitioned over rows; 64-wide butterfly merge on the
// reference (distbits,idx) keys. Unresolved (dist9 >= 0.2494) -> flags2.
__global__ __launch_bounds__(64) void k_wavefb(const float* __restrict__ points,
                                               const float4* __restrict__ sorted,
                                               const int* __restrict__ start,
                                               const float* __restrict__ center,
                                               float* __restrict__ geom,
                                               int* __restrict__ flags2,
                                               const int* __restrict__ list,
                                               const int* __restrict__ listCnt) {
  const int lane = threadIdx.x;
  const int n = *listCnt;
  for (int it = blockIdx.x; it < n; it += gridDim.x) {
    const int e = list[it];
    const int b = e >> 13, qs = e & (N_PTS - 1);
    const float4* SP = sorted + (size_t)b * N_PTS;
    const int* ST = start + b * (NCELL + 1);
    const float4 qp = SP[qs];
    const int qidx = (int)(__float_as_uint(qp.w) & 0x7FFFFFFFu);
    const float px = qp.x, py = qp.y, pz = qp.z;
    const float sqq = sq3(px, py, pz);
    const int cx = cellOf(px), cy = cellOf(py), cz = cellOf(pz);
    const int xlo = max(cx - 8, 0), xhi = min(cx + 8, GDIM - 1);
    const int ylo = max(cy - 8, 0), yhi = min(cy + 8, GDIM - 1);
    const int zlo = max(cz - 8, 0), zhi = min(cz + 8, GDIM - 1);
    const int ycw = yhi - ylo + 1;
    const int Rw = (zhi - zlo + 1) * ycw;

    u64 best[10];
#pragma unroll
    for (int j = 0; j < 10; ++j) best[j] = ((u64)0x7F800000u << 32) | 0xFFFFFFFFu;
    float dens = 0.0f;

    for (int r = lane; r < Rw; r += 64) {
      const int z = zlo + r / ycw, y = ylo + r % ycw;
      const int base = (z * GDIM + y) * GDIM;
      const int j0 = ST[base + xlo], j1 = ST[base + xhi + 1];
      for (int j = j0; j < j1; ++j) {
        const float4 tp = SP[j];
        const unsigned wb = __float_as_uint(tp.w);
        const float sqc = sq3(tp.x, tp.y, tp.z);
        const float dot = __fmaf_rn(pz, tp.z, __fmaf_rn(py, tp.y, __fmul_rn(px, tp.x)));
        const float d2  = __fsub_rn(__fadd_rn(sqq, sqc), __fmul_rn(2.0f, dot));
        const float dist = sqrtf(fmaxf(d2, 0.0f));
        if ((dist < RADIUS_F) && (wb & 0x80000000u)) dens += 1.0f;
        const u64 key = ((u64)__float_as_uint(dist) << 32) | (wb & 0x7FFFFFFFu);
        if (key < best[9]) insert10(best, key);
      }
    }
#pragma unroll
    for (int s = 1; s < 64; s <<= 1) {
      dens += __shfl_xor(dens, s);
      u64 ok[10];
#pragma unroll
      for (int j = 0; j < 10; ++j) ok[j] = __shfl_xor(best[j], s);
#pragma unroll
      for (int j = 0; j < 10; ++j) {
        if (ok[j] < best[9]) insert10(best, ok[j]); else break;
      }
    }
    if (lane == 0) {
      const float dist9 = __uint_as_float((unsigned)(best[9] >> 32));
      if (dist9 < 0.2494f) {
        const float4 ctr = reinterpret_cast<const float4*>(center)[b];
        const float* P = points + (size_t)b * N_PTS * 3;
        int idxs[10];
#pragma unroll
        for (int j = 0; j < 10; ++j) idxs[j] = (int)(((unsigned)best[j]) & 0x7FFFFFFFu);
        geom_epilogue(P, idxs, dens, px, py, pz, ctr, geom + ((size_t)b * N_PTS + qidx) * 6);
      } else {
        flags2[b * N_PTS + qs] = 1;
      }
    }
  }
}

// ---------------------------------------------------------------------------
// Tier-3: exact (dist,idx) ring-scan, gated on flags2 (runs for ~0 queries)
__global__ __launch_bounds__(256) void k_fallback(const float* __restrict__ points,
                                                  const float4* __restrict__ sorted,
                                                  const int* __restrict__ start,
                                                  const float* __restrict__ center,
                                                  float* __restrict__ geom,
                                                  const int* __restrict__ flags2) {
  const int b = blockIdx.y;
  const int qs = blockIdx.x * 256 + threadIdx.x;
  if (flags2[b * N_PTS + qs] == 0) return;
  const float4 qp = sorted[(size_t)b * N_PTS + qs];
  const unsigned qw = __float_as_uint(qp.w);
  const int qidx = (int)(qw & 0x7FFFFFFFu);

  const float px = qp.x, py = qp.y, pz = qp.z;
  const float sqq = sq3(px, py, pz);
  const int cx = cellOf(px), cy = cellOf(py), cz = cellOf(pz);

  const int* ST = start + b * (NCELL + 1);
  const float4* SP = sorted + (size_t)b * N_PTS;

  u64 best[10];
#pragma unroll
  for (int j = 0; j < 10; ++j) best[j] = ((u64)0x7F800000u << 32) | 0xFFFFFFFFu;
  float dens = 0.0f;

  for (int rho = 0; rho < GDIM; ++rho) {
    const int zlo = max(cz - rho, 0), zhi = min(cz + rho, GDIM - 1);
    const int ylo = max(cy - rho, 0), yhi = min(cy + rho, GDIM - 1);
    for (int z = zlo; z <= zhi; ++z) {
      const int adz = abs(z - cz);
      for (int y = ylo; y <= yhi; ++y) {
        const int ady = abs(y - cy);
        const int m2 = max(adz, ady);
        int ja, jb;
        int ja2 = 0, jb2 = 0;
        const int rowBase = (z * GDIM + y) * GDIM;
        if (m2 == rho) {
          const int xa = max(cx - rho, 0), xb = min(cx + rho, GDIM - 1);
          ja = ST[rowBase + xa]; jb = ST[rowBase + xb + 1];
        } else {
          ja = jb = 0;
          if (cx - rho >= 0)        { ja = ST[rowBase + cx - rho]; jb = ST[rowBase + cx - rho + 1]; }
          if (cx + rho <= GDIM - 1) { ja2 = ST[rowBase + cx + rho]; jb2 = ST[rowBase + cx + rho + 1]; }
        }
#pragma unroll 1
        for (int pass = 0; pass < 2; ++pass) {
          const int j0 = pass ? ja2 : ja;
          const int j1 = pass ? jb2 : jb;
          for (int j = j0; j < j1; ++j) {
            const float4 tp = SP[j];
            const unsigned wb = __float_as_uint(tp.w);
            const float sqc = sq3(tp.x, tp.y, tp.z);
            const float dot = __fmaf_rn(pz, tp.z, __fmaf_rn(py, tp.y, __fmul_rn(px, tp.x)));
            const float d2  = __fsub_rn(__fadd_rn(sqq, sqc), __fmul_rn(2.0f, dot));
            const float dist = sqrtf(fmaxf(d2, 0.0f));
            if ((dist < RADIUS_F) && (wb & 0x80000000u)) dens += 1.0f;
            const u64 key = ((u64)__float_as_uint(dist) << 32) | (wb & 0x7FFFFFFFu);
            if (key < best[9]) insert10(best, key);
          }
        }
      }
    }
    if (rho >= 1) {
      const float dist9 = __uint_as_float((unsigned)(best[9] >> 32));
      if (dist9 < (float)rho * HCELL * 0.999f) break;
    }
  }

  const float4 ctr = reinterpret_cast<const float4*>(center)[b];
  const float* P = points + (size_t)b * N_PTS * 3;
  int idxs[10];
#pragma unroll
  for (int j = 0; j < 10; ++j) idxs[j] = (int)(((unsigned)best[j]) & 0x7FFFFFFFu);
  geom_epilogue(P, idxs, dens, px, py, pz, ctr, geom + ((size_t)b * N_PTS + qidx) * 6);
}

// ---------------------------------------------------------------------------
// Kernel 3: fused 2-layer MLP (unchanged).
__global__ __launch_bounds__(256) void k_mlp(const float* __restrict__ features,
                                             const float* __restrict__ geom,
                                             const float* __restrict__ W1,
                                             const float* __restrict__ b1,
                                             const float* __restrict__ W2,
                                             const float* __restrict__ b2,
                                             float* __restrict__ out) {
  __shared__ float A[64][74];
  __shared__ float H[64][130];
  const int tid = threadIdx.x;
  const int row0 = blockIdx.x * 64;

  for (int i = tid; i < 64 * IN_DIM; i += 256) {
    int r = i >> 6, k = i & 63;
    A[r][k] = features[(size_t)(row0 + r) * IN_DIM + k];
  }
  for (int i = tid; i < 64 * 8; i += 256) {
    int r = i >> 3, k = i & 7;
    if (k < 6) A[r][IN_DIM + k] = geom[(size_t)(row0 + r) * 6 + k];
  }
  __syncthreads();

  const int ty = tid >> 4;
  const int tx = tid & 15;

  float acc[4][8];
#pragma unroll
  for (int i = 0; i < 4; ++i)
#pragma unroll
    for (int j = 0; j < 8; ++j) acc[i][j] = 0.0f;

#pragma unroll 2
  for (int k = 0; k < D_IN; ++k) {
    float a[4];
#pragma unroll
    for (int i = 0; i < 4; ++i) a[i] = A[ty * 4 + i][k];
    float4 w0 = *reinterpret_cast<const float4*>(&W1[(size_t)k * ODIM + tx * 8]);
    float4 w1 = *reinterpret_cast<const float4*>(&W1[(size_t)k * ODIM + tx * 8 + 4]);
    float w[8] = {w0.x, w0.y, w0.z, w0.w, w1.x, w1.y, w1.z, w1.w};
#pragma unroll
    for (int i = 0; i < 4; ++i)
#pragma unroll
      for (int j = 0; j < 8; ++j) acc[i][j] = fmaf(a[i], w[j], acc[i][j]);
  }

  {
    float4 bb0 = *reinterpret_cast<const float4*>(&b1[tx * 8]);
    float4 bb1 = *reinterpret_cast<const float4*>(&b1[tx * 8 + 4]);
    float bb[8] = {bb0.x, bb0.y, bb0.z, bb0.w, bb1.x, bb1.y, bb1.z, bb1.w};
#pragma unroll
    for (int i = 0; i < 4; ++i) {
      float4 h0 = make_float4(fmaxf(acc[i][0] + bb[0], 0.f), fmaxf(acc[i][1] + bb[1], 0.f),
                              fmaxf(acc[i][2] + bb[2], 0.f), fmaxf(acc[i][3] + bb[3], 0.f));
      float4 h1 = make_float4(fmaxf(acc[i][4] + bb[4], 0.f), fmaxf(acc[i][5] + bb[5], 0.f),
                              fmaxf(acc[i][6] + bb[6], 0.f), fmaxf(acc[i][7] + bb[7], 0.f));
      *reinterpret_cast<float4*>(&H[ty * 4 + i][tx * 8]) = h0;
      *reinterpret_cast<float4*>(&H[ty * 4 + i][tx * 8 + 4]) = h1;
    }
  }
  __syncthreads();

#pragma unroll
  for (int i = 0; i < 4; ++i)
#pragma unroll
    for (int j = 0; j < 8; ++j) acc[i][j] = 0.0f;

#pragma unroll 2
  for (int k = 0; k < ODIM; ++k) {
    float a[4];
#pragma unroll
    for (int i = 0; i < 4; ++i) a[i] = H[ty * 4 + i][k];
    float4 w0 = *reinterpret_cast<const float4*>(&W2[(size_t)k * ODIM + tx * 8]);
    float4 w1 = *reinterpret_cast<const float4*>(&W2[(size_t)k * ODIM + tx * 8 + 4]);
    float w[8] = {w0.x, w0.y, w0.z, w0.w, w1.x, w1.y, w1.z, w1.w};
#pragma unroll
    for (int i = 0; i < 4; ++i)
#pragma unroll
      for (int j = 0; j < 8; ++j) acc[i][j] = fmaf(a[i], w[j], acc[i][j]);
  }

  {
    float4 bb0 = *reinterpret_cast<const float4*>(&b2[tx * 8]);
    float4 bb1 = *reinterpret_cast<const float4*>(&b2[tx * 8 + 4]);
    float bb[8] = {bb0.x, bb0.y, bb0.z, bb0.w, bb1.x, bb1.y, bb1.z, bb1.w};
#pragma unroll
    for (int i = 0; i < 4; ++i) {
      size_t row = (size_t)(row0 + ty * 4 + i);
      float4 o0 = make_float4(fmaxf(acc[i][0] + bb[0], 0.f), fmaxf(acc[i][1] + bb[1], 0.f),
                              fmaxf(acc[i][2] + bb[2], 0.f), fmaxf(acc[i][3] + bb[3], 0.f));
      float4 o1 = make_float4(fmaxf(acc[i][4] + bb[4], 0.f), fmaxf(acc[i][5] + bb[5], 0.f),
                              fmaxf(acc[i][6] + bb[6], 0.f), fmaxf(acc[i][7] + bb[7], 0.f));
      *reinterpret_cast<float4*>(&out[row * ODIM + tx * 8]) = o0;
      *reinterpret_cast<float4*>(&out[row * ODIM + tx * 8 + 4]) = o1;
    }
  }
}

// ---------------------------------------------------------------------------
extern "C" void kernel_launch(void* const* d_in, const int* in_sizes, int n_in,
                              void* d_out, int out_size, void* d_ws, size_t ws_size,
                              hipStream_t stream) {
  const float* points   = (const float*)d_in[0];
  const float* features = (const float*)d_in[1];
  const int*   mask     = (const int*)d_in[2];
  const float* W1       = (const float*)d_in[3];
  const float* b1       = (const float*)d_in[4];
  const float* W2       = (const float*)d_in[5];
  const float* b2       = (const float*)d_in[6];
  float* out = (float*)d_out;

  // exact density threshold: dist < R  <=>  d2c < DENS_T  (validated R4)
  const double Rd   = (double)0.02f;
  const double midd = Rd - ldexp(1.0, -30);     // halfway(pred(R), R)
  const double Td   = midd * midd;
  float densT = (float)Td;
  if ((double)densT <= Td) densT = nextafterf(densT, 1.0f);
  const float collectT = 0.0935f * 0.0935f;     // collect radius^2 (< (3h)^2 with margin)
  const float thrCheck = 0.0934f;               // completeness check on dist9

  // ws layout (256B aligned). countBuf+flags2+listCnt contiguous for one memset.
  char* w = (char*)d_ws;
  size_t off = 0;
  auto take = [&](size_t bytes) { char* p = w + off; off = (off + bytes + 255) & ~(size_t)255; return p; };
  float*  geomBuf   = (float*)take((size_t)NQ_ALL * 6 * 4);
  float*  centerBuf = (float*)take(2 * 16);
  char*   zero0     = (char*)take(0);
  int*    countBuf  = (int*)take((size_t)B_SZ * NCELL * 4);
  int*    flags2Buf = (int*)take((size_t)NQ_ALL * 4);
  int*    listCnt   = (int*)take(4);
  char*   zero1     = (char*)take(0);
  int*    startBuf  = (int*)take((size_t)B_SZ * (NCELL + 1) * 4);
  int*    curBuf    = (int*)take((size_t)B_SZ * NCELL * 4);
  float4* sortedBuf = (float4*)take((size_t)B_SZ * N_PTS * 16);
  int*    listBuf   = (int*)take((size_t)NQ_ALL * 4);
  (void)ws_size;

  hipMemsetAsync(zero0, 0, (size_t)(zero1 - zero0), stream);
  k_center<<<B_SZ, 256, 0, stream>>>(points, mask, centerBuf);
  k_grid_count<<<NQ_ALL / 256, 256, 0, stream>>>(points, countBuf);
  k_scan<<<B_SZ, 1024, 0, stream>>>(countBuf, startBuf, curBuf);
  k_scatter<<<NQ_ALL / 256, 256, 0, stream>>>(points, mask, curBuf, sortedBuf);
  k_collect<<<dim3(NSUPER, B_SZ), 64, 0, stream>>>(points, sortedBuf, startBuf, centerBuf,
                                                   geomBuf, listBuf, listCnt,
                                                   collectT, densT, thrCheck);
  k_wavefb<<<1024, 64, 0, stream>>>(points, sortedBuf, startBuf, centerBuf,
                                    geomBuf, flags2Buf, listBuf, listCnt);
  k_fallback<<<dim3(N_PTS / 256, B_SZ), 256, 0, stream>>>(points, sortedBuf, startBuf,
                                                          centerBuf, geomBuf, flags2Buf);
  k_mlp<<<NQ_ALL / 64, 256, 0, stream>>>(features, geomBuf, W1, b1, W2, b2, out);
}

// Round 6
// 186.523 us; speedup vs baseline: 2.0075x; 1.2181x over previous
//
#include <hip/hip_runtime.h>
#include <math.h>
#include <stdint.h>

#define B_SZ   2
#define N_PTS  8192
#define IN_DIM 64
#define D_IN   70          // 64 features + 6 geom
#define ODIM   128
#define NQ_ALL (B_SZ * N_PTS)
#define RADIUS_F 0.02f

#define GDIM  32
#define NCELL (GDIM * GDIM * GDIM)
#define HCELL 0.03125f     // 1/32, exact in f32

#define SUP     4                       // base cells per supercell axis (exact tiling)
#define NSUP_AX 8
#define NSUPER  (NSUP_AX * NSUP_AX * NSUP_AX)   // 512
#define SCAP    352                     // staged halo capacity (lambda 250 + 6 sigma)
#define LCAP    24                      // per-lane collect buffer (lambda 7)
#define MAXROWS 100                     // 10x10 halo (z,y) rows max

#define MROWS   32                      // k_mlp rows per block

typedef unsigned long long u64;

// ---------------------------------------------------------------------------
__device__ __forceinline__ void insert11(u64 (&best)[11], u64 key) {
#pragma unroll
  for (int j = 10; j >= 1; --j) {
    u64 hi = (best[j - 1] > key) ? best[j - 1] : key;
    best[j] = (best[j] < hi) ? best[j] : hi;
  }
  best[0] = (best[0] < key) ? best[0] : key;
}
__device__ __forceinline__ void insert10(u64 (&best)[10], u64 key) {
#pragma unroll
  for (int j = 9; j >= 1; --j) {
    u64 hi = (best[j - 1] > key) ? best[j - 1] : key;
    best[j] = (best[j] < hi) ? best[j] : hi;
  }
  best[0] = (best[0] < key) ? best[0] : key;
}

// exact f32 helpers matching the reference's op order (no contraction)
__device__ __forceinline__ float sq3(float x, float y, float z) {
  return __fadd_rn(__fadd_rn(__fmul_rn(x, x), __fmul_rn(y, y)), __fmul_rn(z, z));
}

__device__ __forceinline__ int cellOf(float v) {
  int c = (int)(v * 32.0f);            // v*32 is exact (power-of-2 scale)
  return min(max(c, 0), GDIM - 1);
}

// shared epilogue: covariance over the 10 NN (exact f64) + eigen + geometry
__device__ __forceinline__ void geom_epilogue(const float* __restrict__ P,
                                              const int (&idxs)[10], float dens,
                                              float px, float py, float pz,
                                              float4 ctr, float* __restrict__ g) {
  double c00 = 0, c01 = 0, c02 = 0, c11 = 0, c12 = 0, c22 = 0;
#pragma unroll
  for (int j = 0; j < 10; ++j) {
    const int idx = idxs[j];
    const float nx = P[3 * idx + 0], ny = P[3 * idx + 1], nz = P[3 * idx + 2];
    const float ex = __fsub_rn(nx, px);
    const float ey = __fsub_rn(ny, py);
    const float ez = __fsub_rn(nz, pz);
    c00 += (double)ex * ex; c01 += (double)ex * ey; c02 += (double)ex * ez;
    c11 += (double)ey * ey; c12 += (double)ey * ez; c22 += (double)ez * ez;
  }
  const double a00 = c00 / 10.0, a01 = c01 / 10.0, a02 = c02 / 10.0;
  const double a11 = c11 / 10.0, a12 = c12 / 10.0, a22 = c22 / 10.0;

  double p1 = a01 * a01 + a02 * a02 + a12 * a12;
  double qq = (a00 + a11 + a22) / 3.0;
  double p2 = (a00 - qq) * (a00 - qq) + (a11 - qq) * (a11 - qq) +
              (a22 - qq) * (a22 - qq) + 2.0 * p1;
  double ev0, ev2;
  if (p2 <= 1e-60) {
    ev0 = ev2 = qq;
  } else {
    double p = sqrt(p2 / 6.0);
    double invp = 1.0 / p;
    double b00 = (a00 - qq) * invp, b11 = (a11 - qq) * invp, b22 = (a22 - qq) * invp;
    double b01 = a01 * invp, b02 = a02 * invp, b12 = a12 * invp;
    double detB = b00 * (b11 * b22 - b12 * b12) - b01 * (b01 * b22 - b12 * b02) +
                  b02 * (b01 * b12 - b11 * b02);
    double r = 0.5 * detB;
    r = fmin(1.0, fmax(-1.0, r));
    double phi = acos(r) / 3.0;
    ev2 = qq + 2.0 * p * cos(phi);
    ev0 = qq + 2.0 * p * cos(phi + 2.0943951023931953);  // +2*pi/3
  }
  const float curv = (float)(ev0 / (ev2 + 1e-08));

  const bool on = ctr.w > 0.0f;
  const float rx = __fsub_rn(px, ctr.x);
  const float ry = __fsub_rn(py, ctr.y);
  const float rz = __fsub_rn(pz, ctr.z);
  const float dist_c = sqrtf(sq3(rx, ry, rz));
  const float horiz  = sqrtf(__fadd_rn(__fmul_rn(rx, rx), __fmul_rn(ry, ry)));
  const float rad    = atan2f(ry, rx);

  g[0] = on ? dist_c : 0.0f;
  g[1] = on ? rz : 0.0f;
  g[2] = on ? horiz : 0.0f;
  g[3] = on ? dens : 0.0f;
  g[4] = on ? curv : 0.0f;
  g[5] = on ? rad : 0.0f;
}

// ---------------------------------------------------------------------------
// k_build: fused grid count + masked-centroid partial reduction.
// ctrAcc[b*4+{0,1,2,3}] accumulated via f64 atomics (order-noise <= 1 ulp).
__global__ __launch_bounds__(256) void k_build(const float* __restrict__ points,
                                               const int* __restrict__ mask,
                                               int* __restrict__ count,
                                               double* __restrict__ ctrAcc) {
  const int t = blockIdx.x * 256 + threadIdx.x;
  const int b = t >> 13;                 // constant within a block (32 blocks/batch)
  const int i = t & (N_PTS - 1);
  const float* P = points + (size_t)b * N_PTS * 3;
  const float x = P[3 * i + 0], y = P[3 * i + 1], z = P[3 * i + 2];
  atomicAdd(&count[b * NCELL + (cellOf(z) * GDIM + cellOf(y)) * GDIM + cellOf(x)], 1);

  const bool m = mask[b * N_PTS + i] != 0;
  double vx = m ? (double)x : 0.0, vy = m ? (double)y : 0.0;
  double vz = m ? (double)z : 0.0, vc = m ? 1.0 : 0.0;
#pragma unroll
  for (int s = 1; s < 64; s <<= 1) {
    vx += __shfl_xor(vx, s); vy += __shfl_xor(vy, s);
    vz += __shfl_xor(vz, s); vc += __shfl_xor(vc, s);
  }
  __shared__ double sh[4][4];
  const int w = threadIdx.x >> 6;
  if ((threadIdx.x & 63) == 0) { sh[0][w] = vx; sh[1][w] = vy; sh[2][w] = vz; sh[3][w] = vc; }
  __syncthreads();
  if (threadIdx.x == 0) {
    atomicAdd(&ctrAcc[b * 4 + 0], sh[0][0] + sh[0][1] + sh[0][2] + sh[0][3]);
    atomicAdd(&ctrAcc[b * 4 + 1], sh[1][0] + sh[1][1] + sh[1][2] + sh[1][3]);
    atomicAdd(&ctrAcc[b * 4 + 2], sh[2][0] + sh[2][1] + sh[2][2] + sh[2][3]);
    atomicAdd(&ctrAcc[b * 4 + 3], sh[3][0] + sh[3][1] + sh[3][2] + sh[3][3]);
  }
}

// one block of 1024 threads per batch; exclusive scan of 32768 counts.
// Thread 0 also finalizes the f32 center from ctrAcc.
__global__ __launch_bounds__(1024) void k_scan(const int* __restrict__ count,
                                               int* __restrict__ start,
                                               int* __restrict__ cur,
                                               const double* __restrict__ ctrAcc,
                                               float* __restrict__ centerOut) {
  const int b = blockIdx.x;
  const int t = threadIdx.x;
  if (t == 0) {
    const float cf = (float)ctrAcc[b * 4 + 3];
    const float div = fmaxf(cf, 1.0f);
    centerOut[b * 4 + 0] = (float)ctrAcc[b * 4 + 0] / div;
    centerOut[b * 4 + 1] = (float)ctrAcc[b * 4 + 1] / div;
    centerOut[b * 4 + 2] = (float)ctrAcc[b * 4 + 2] / div;
    centerOut[b * 4 + 3] = (cf > 0.0f) ? 1.0f : 0.0f;
  }
  int c[32]; int sum = 0;
#pragma unroll
  for (int j = 0; j < 32; ++j) { c[j] = count[b * NCELL + t * 32 + j]; sum += c[j]; }
  __shared__ int s[1024];
  s[t] = sum;
  __syncthreads();
  for (int off = 1; off < 1024; off <<= 1) {
    int v = (t >= off) ? s[t - off] : 0;
    __syncthreads();
    if (t >= off) s[t] += v;
    __syncthreads();
  }
  int excl = (t > 0) ? s[t - 1] : 0;
#pragma unroll
  for (int j = 0; j < 32; ++j) {
    start[b * (NCELL + 1) + t * 32 + j] = excl;
    cur[b * NCELL + t * 32 + j] = excl;
    excl += c[j];
  }
  if (t == 1023) start[b * (NCELL + 1) + NCELL] = excl;
}

__global__ __launch_bounds__(256) void k_scatter(const float* __restrict__ points,
                                                 const int* __restrict__ mask,
                                                 int* __restrict__ cur,
                                                 float4* __restrict__ sorted) {
  const int t = blockIdx.x * 256 + threadIdx.x;
  const int b = t >> 13;
  const int i = t & (N_PTS - 1);
  const float* P = points + (size_t)b * N_PTS * 3;
  const float x = P[3 * i + 0], y = P[3 * i + 1], z = P[3 * i + 2];
  const int cell = (cellOf(z) * GDIM + cellOf(y)) * GDIM + cellOf(x);
  const int pos = atomicAdd(&cur[b * NCELL + cell], 1);
  const unsigned wb = (unsigned)i | ((mask[b * N_PTS + i] != 0) ? 0x80000000u : 0u);
  sorted[(size_t)b * N_PTS + pos] = make_float4(x, y, z, __uint_as_float(wb));
}

// ---------------------------------------------------------------------------
// Kernel C: collect-then-sort, 2 waves per supercell (block=128). Wave 0 does
// the prefix bookkeeping; both waves stage the +-3-cell halo and process query
// slots (32 per pass: 4 lanes/query). Per-pair math and tier checks identical
// to R4/R5 (validated exact).
__global__ __launch_bounds__(128) void k_collect(const float* __restrict__ points,
                                                 const float4* __restrict__ sorted,
                                                 const int* __restrict__ start,
                                                 const float* __restrict__ center,
                                                 float* __restrict__ geom,
                                                 int* __restrict__ list,
                                                 int* __restrict__ listCnt,
                                                 float COLLECT_T, float DENS_T,
                                                 float THR_CHECK) {
  const int b  = blockIdx.y;
  const int sc = blockIdx.x;
  const int sx = sc & 7, sy = (sc >> 3) & 7, sz = sc >> 6;
  const int tid = threadIdx.x;           // 0..127

  const int* ST = start + b * (NCELL + 1);
  const float4* SP = sorted + (size_t)b * N_PTS;

  const int x0 = SUP * sx, x1 = SUP * sx + SUP - 1;
  const int y0 = SUP * sy, y1 = SUP * sy + SUP - 1;
  const int z0 = SUP * sz, z1 = SUP * sz + SUP - 1;
  const int hx0 = max(x0 - 3, 0), hx1 = min(x1 + 3, GDIM - 1);
  const int hy0 = max(y0 - 3, 0), hy1 = min(y1 + 3, GDIM - 1);
  const int hz0 = max(z0 - 3, 0), hz1 = min(z1 + 3, GDIM - 1);
  const int yc = hy1 - hy0 + 1;               // <=10
  const int R  = (hz1 - hz0 + 1) * yc;        // <=100

  __shared__ int    rs[MAXROWS], rp[MAXROWS + 1];
  __shared__ int    qs_[16], qp_[17];
  __shared__ float4 pts4[SCAP];
  __shared__ u64    lbuf[128 * LCAP];

  if (tid < 64) {
    // query rows: exactly 16 (4 z x 4 y); lane<16 owns row `lane`
    {
      int qlen = 0, qst = 0;
      if (tid < 16) {
        const int z = z0 + (tid >> 2), y = y0 + (tid & 3);
        const int base = (z * GDIM + y) * GDIM;
        qst  = ST[base + x0];
        qlen = ST[base + x1 + 1] - qst;
      }
      int inc = qlen;
      for (int off = 1; off < 64; off <<= 1) { int v = __shfl_up(inc, off); if (tid >= off) inc += v; }
      if (tid < 16) { qs_[tid] = qst; qp_[tid] = inc - qlen; }
      if (tid == 63) qp_[16] = inc;
    }
    // halo rows: 2 per lane, in row order
    {
      int len[2] = {0, 0}, st2[2] = {0, 0};
#pragma unroll
      for (int k = 0; k < 2; ++k) {
        const int r = tid * 2 + k;
        if (r < R) {
          const int z = hz0 + r / yc, y = hy0 + r % yc;
          const int base = (z * GDIM + y) * GDIM;
          st2[k] = ST[base + hx0];
          len[k] = ST[base + hx1 + 1] - st2[k];
        }
      }
      int sum = len[0] + len[1];
      int inc = sum;
      for (int off = 1; off < 64; off <<= 1) { int v = __shfl_up(inc, off); if (tid >= off) inc += v; }
      int exc = inc - sum;
#pragma unroll
      for (int k = 0; k < 2; ++k) {
        const int r = tid * 2 + k;
        if (r < R) { rs[r] = st2[k]; rp[r] = exc; }
        exc += len[k];
      }
      if (tid == 63) rp[R] = inc;
    }
  }
  __syncthreads();

  const int C    = rp[R];
  const int qtot = qp_[16];
  if (qtot == 0) return;

  if (C > SCAP) {                 // astronomically rare: all queries to tier-2
    for (int t = tid; t < qtot; t += 128) {
      int lo = 0, hi = 15;
      while (lo < hi) { const int mid = (lo + hi + 1) >> 1; if (qp_[mid] <= t) lo = mid; else hi = mid - 1; }
      const int qglob = qs_[lo] + (t - qp_[lo]);
      const int pos = atomicAdd(listCnt, 1);
      list[pos] = (b << 13) | qglob;
    }
    return;
  }

  for (int i = tid; i < C; i += 128) {   // stage halo
    int lo = 0, hi = R - 1;
    while (lo < hi) { const int mid = (lo + hi + 1) >> 1; if (rp[mid] <= i) lo = mid; else hi = mid - 1; }
    pts4[i] = SP[rs[lo] + (i - rp[lo])];
  }
  __syncthreads();

  const float4 ctr = reinterpret_cast<const float4*>(center)[b];
  const float* P = points + (size_t)b * N_PTS * 3;
  const int sub = tid & 3;      // 4 lanes per query
  const int gq  = tid >> 2;     // 32 query slots per pass

  for (int q0 = 0; q0 < qtot; q0 += 32) {
    const int myq = q0 + gq;
    const bool act = (myq < qtot);
    const int mq = act ? myq : 0;
    int lo = 0, hi = 15;
    while (lo < hi) { const int mid = (lo + hi + 1) >> 1; if (qp_[mid] <= mq) lo = mid; else hi = mid - 1; }
    const int qglob = qs_[lo] + (mq - qp_[lo]);
    const float4 qp4 = SP[qglob];
    const int qidx = (int)(__float_as_uint(qp4.w) & 0x7FFFFFFFu);
    const float px = qp4.x, py = qp4.y, pz = qp4.z;
    const float sqq = sq3(px, py, pz);

    int cnt = 0;
    u64* myb = &lbuf[tid * LCAP];
#pragma unroll 2
    for (int j = sub; j < C; j += 4) {
      const float4 tp = pts4[j];                      // broadcast, conflict-free
      const float sqc = sq3(tp.x, tp.y, tp.z);
      const float dot = __fmaf_rn(pz, tp.z, __fmaf_rn(py, tp.y, __fmul_rn(px, tp.x)));
      const float d2  = __fsub_rn(__fadd_rn(sqq, sqc), __fmul_rn(2.0f, dot));
      const float d2c = fmaxf(d2, 0.0f);
      if (d2c < COLLECT_T) {
        if (cnt < LCAP) {
          const unsigned wb = __float_as_uint(tp.w);
          myb[cnt] = ((u64)__float_as_uint(d2c) << 32)
                   | (u64)(((wb & 0x7FFFFFFFu) << 1) | (wb >> 31));
        }
        ++cnt;
      }
    }

    // per-lane finalize from buffer
    u64 best[11];
#pragma unroll
    for (int j = 0; j < 11; ++j) best[j] = ~0ull;
    float dens = 0.0f;
    const int m = min(cnt, LCAP);
    for (int i = 0; i < m; ++i) {
      const u64 e = myb[i];
      if ((e & 1ull) && __uint_as_float((unsigned)(e >> 32)) < DENS_T) dens += 1.0f;
      if (e < best[10]) insert11(best, e);
    }
    int cntg = cnt;
    int over = (cnt > LCAP) ? 1 : 0;
    // 2-step butterfly merge within the 4-lane group
#pragma unroll
    for (int s = 1; s < 4; s <<= 1) {
      dens += __shfl_xor(dens, s);
      cntg += __shfl_xor(cntg, s);
      over |= __shfl_xor(over, s);
      u64 ok[11];
#pragma unroll
      for (int j = 0; j < 11; ++j) ok[j] = __shfl_xor(best[j], s);
#pragma unroll
      for (int j = 0; j < 11; ++j) {
        if (ok[j] < best[10]) insert11(best, ok[j]); else break;
      }
    }

    if (act && sub == 0) {
      const float dist9 = sqrtf(__uint_as_float((unsigned)(best[9] >> 32)));
      bool bad = (over != 0) || (cntg < 10) || !(dist9 < THR_CHECK);
      if (cntg >= 11) {
        const float dist10 = sqrtf(__uint_as_float((unsigned)(best[10] >> 32)));
        bad = bad || (dist10 == dist9);
      }
      if (bad) {
        const int pos = atomicAdd(listCnt, 1);
        list[pos] = (b << 13) | qglob;
      } else {
        int idxs[10];
#pragma unroll
        for (int j = 0; j < 10; ++j) idxs[j] = (int)(((unsigned)best[j]) >> 1);
        geom_epilogue(P, idxs, dens, px, py, pz, ctr,
                      geom + ((size_t)b * N_PTS + qidx) * 6);
      }
    }
  }
}

// ---------------------------------------------------------------------------
// Tier-2: one wave per flagged query (grid-stride over compacted list).
__global__ __launch_bounds__(64) void k_wavefb(const float* __restrict__ points,
                                               const float4* __restrict__ sorted,
                                               const int* __restrict__ start,
                                               const float* __restrict__ center,
                                               float* __restrict__ geom,
                                               int* __restrict__ flags2,
                                               const int* __restrict__ list,
                                               const int* __restrict__ listCnt) {
  const int lane = threadIdx.x;
  const int n = *listCnt;
  for (int it = blockIdx.x; it < n; it += gridDim.x) {
    const int e = list[it];
    const int b = e >> 13, qs = e & (N_PTS - 1);
    const float4* SP = sorted + (size_t)b * N_PTS;
    const int* ST = start + b * (NCELL + 1);
    const float4 qp = SP[qs];
    const int qidx = (int)(__float_as_uint(qp.w) & 0x7FFFFFFFu);
    const float px = qp.x, py = qp.y, pz = qp.z;
    const float sqq = sq3(px, py, pz);
    const int cx = cellOf(px), cy = cellOf(py), cz = cellOf(pz);
    const int xlo = max(cx - 8, 0), xhi = min(cx + 8, GDIM - 1);
    const int ylo = max(cy - 8, 0), yhi = min(cy + 8, GDIM - 1);
    const int zlo = max(cz - 8, 0), zhi = min(cz + 8, GDIM - 1);
    const int ycw = yhi - ylo + 1;
    const int Rw = (zhi - zlo + 1) * ycw;

    u64 best[10];
#pragma unroll
    for (int j = 0; j < 10; ++j) best[j] = ((u64)0x7F800000u << 32) | 0xFFFFFFFFu;
    float dens = 0.0f;

    for (int r = lane; r < Rw; r += 64) {
      const int z = zlo + r / ycw, y = ylo + r % ycw;
      const int base = (z * GDIM + y) * GDIM;
      const int j0 = ST[base + xlo], j1 = ST[base + xhi + 1];
      for (int j = j0; j < j1; ++j) {
        const float4 tp = SP[j];
        const unsigned wb = __float_as_uint(tp.w);
        const float sqc = sq3(tp.x, tp.y, tp.z);
        const float dot = __fmaf_rn(pz, tp.z, __fmaf_rn(py, tp.y, __fmul_rn(px, tp.x)));
        const float d2  = __fsub_rn(__fadd_rn(sqq, sqc), __fmul_rn(2.0f, dot));
        const float dist = sqrtf(fmaxf(d2, 0.0f));
        if ((dist < RADIUS_F) && (wb & 0x80000000u)) dens += 1.0f;
        const u64 key = ((u64)__float_as_uint(dist) << 32) | (wb & 0x7FFFFFFFu);
        if (key < best[9]) insert10(best, key);
      }
    }
#pragma unroll
    for (int s = 1; s < 64; s <<= 1) {
      dens += __shfl_xor(dens, s);
      u64 ok[10];
#pragma unroll
      for (int j = 0; j < 10; ++j) ok[j] = __shfl_xor(best[j], s);
#pragma unroll
      for (int j = 0; j < 10; ++j) {
        if (ok[j] < best[9]) insert10(best, ok[j]); else break;
      }
    }
    if (lane == 0) {
      const float dist9 = __uint_as_float((unsigned)(best[9] >> 32));
      if (dist9 < 0.2494f) {
        const float4 ctr = reinterpret_cast<const float4*>(center)[b];
        const float* P = points + (size_t)b * N_PTS * 3;
        int idxs[10];
#pragma unroll
        for (int j = 0; j < 10; ++j) idxs[j] = (int)(((unsigned)best[j]) & 0x7FFFFFFFu);
        geom_epilogue(P, idxs, dens, px, py, pz, ctr, geom + ((size_t)b * N_PTS + qidx) * 6);
      } else {
        flags2[b * N_PTS + qs] = 1;
      }
    }
  }
}

// ---------------------------------------------------------------------------
// Tier-3: exact (dist,idx) ring-scan, gated on flags2 (runs for ~0 queries)
__global__ __launch_bounds__(256) void k_fallback(const float* __restrict__ points,
                                                  const float4* __restrict__ sorted,
                                                  const int* __restrict__ start,
                                                  const float* __restrict__ center,
                                                  float* __restrict__ geom,
                                                  const int* __restrict__ flags2) {
  const int b = blockIdx.y;
  const int qs = blockIdx.x * 256 + threadIdx.x;
  if (flags2[b * N_PTS + qs] == 0) return;
  const float4 qp = sorted[(size_t)b * N_PTS + qs];
  const unsigned qw = __float_as_uint(qp.w);
  const int qidx = (int)(qw & 0x7FFFFFFFu);

  const float px = qp.x, py = qp.y, pz = qp.z;
  const float sqq = sq3(px, py, pz);
  const int cx = cellOf(px), cy = cellOf(py), cz = cellOf(pz);

  const int* ST = start + b * (NCELL + 1);
  const float4* SP = sorted + (size_t)b * N_PTS;

  u64 best[10];
#pragma unroll
  for (int j = 0; j < 10; ++j) best[j] = ((u64)0x7F800000u << 32) | 0xFFFFFFFFu;
  float dens = 0.0f;

  for (int rho = 0; rho < GDIM; ++rho) {
    const int zlo = max(cz - rho, 0), zhi = min(cz + rho, GDIM - 1);
    const int ylo = max(cy - rho, 0), yhi = min(cy + rho, GDIM - 1);
    for (int z = zlo; z <= zhi; ++z) {
      const int adz = abs(z - cz);
      for (int y = ylo; y <= yhi; ++y) {
        const int ady = abs(y - cy);
        const int m2 = max(adz, ady);
        int ja, jb;
        int ja2 = 0, jb2 = 0;
        const int rowBase = (z * GDIM + y) * GDIM;
        if (m2 == rho) {
          const int xa = max(cx - rho, 0), xb = min(cx + rho, GDIM - 1);
          ja = ST[rowBase + xa]; jb = ST[rowBase + xb + 1];
        } else {
          ja = jb = 0;
          if (cx - rho >= 0)        { ja = ST[rowBase + cx - rho]; jb = ST[rowBase + cx - rho + 1]; }
          if (cx + rho <= GDIM - 1) { ja2 = ST[rowBase + cx + rho]; jb2 = ST[rowBase + cx + rho + 1]; }
        }
#pragma unroll 1
        for (int pass = 0; pass < 2; ++pass) {
          const int j0 = pass ? ja2 : ja;
          const int j1 = pass ? jb2 : jb;
          for (int j = j0; j < j1; ++j) {
            const float4 tp = SP[j];
            const unsigned wb = __float_as_uint(tp.w);
            const float sqc = sq3(tp.x, tp.y, tp.z);
            const float dot = __fmaf_rn(pz, tp.z, __fmaf_rn(py, tp.y, __fmul_rn(px, tp.x)));
            const float d2  = __fsub_rn(__fadd_rn(sqq, sqc), __fmul_rn(2.0f, dot));
            const float dist = sqrtf(fmaxf(d2, 0.0f));
            if ((dist < RADIUS_F) && (wb & 0x80000000u)) dens += 1.0f;
            const u64 key = ((u64)__float_as_uint(dist) << 32) | (wb & 0x7FFFFFFFu);
            if (key < best[9]) insert10(best, key);
          }
        }
      }
    }
    if (rho >= 1) {
      const float dist9 = __uint_as_float((unsigned)(best[9] >> 32));
      if (dist9 < (float)rho * HCELL * 0.999f) break;
    }
  }

  const float4 ctr = reinterpret_cast<const float4*>(center)[b];
  const float* P = points + (size_t)b * N_PTS * 3;
  int idxs[10];
#pragma unroll
  for (int j = 0; j < 10; ++j) idxs[j] = (int)(((unsigned)best[j]) & 0x7FFFFFFFu);
  geom_epilogue(P, idxs, dens, px, py, pz, ctr, geom + ((size_t)b * N_PTS + qidx) * 6);
}

// ---------------------------------------------------------------------------
// Kernel 3: fused 2-layer MLP, 32-row tiles (512 blocks), 2 rows x 8 cols per
// thread. Odd LDS strides (71/133) -> conflict-free broadcasts. FMA chain per
// output is ascending-k, identical to prior rounds.
__global__ __launch_bounds__(256) void k_mlp(const float* __restrict__ features,
                                             const float* __restrict__ geom,
                                             const float* __restrict__ W1,
                                             const float* __restrict__ b1,
                                             const float* __restrict__ W2,
                                             const float* __restrict__ b2,
                                             float* __restrict__ out) {
  __shared__ float A[MROWS][71];
  __shared__ float H[MROWS][133];
  const int tid = threadIdx.x;
  const int row0 = blockIdx.x * MROWS;

  for (int i = tid; i < MROWS * IN_DIM; i += 256) {
    int r = i >> 6, k = i & 63;
    A[r][k] = features[(size_t)(row0 + r) * IN_DIM + k];
  }
  for (int i = tid; i < MROWS * 8; i += 256) {
    int r = i >> 3, k = i & 7;
    if (k < 6) A[r][IN_DIM + k] = geom[(size_t)(row0 + r) * 6 + k];
  }
  __syncthreads();

  const int r0 = tid >> 4;          // rows r0 and r0+16
  const int c  = (tid & 15) * 8;    // 8 cols

  float acc[2][8];
#pragma unroll
  for (int i = 0; i < 2; ++i)
#pragma unroll
    for (int j = 0; j < 8; ++j) acc[i][j] = 0.0f;

#pragma unroll 2
  for (int k = 0; k < D_IN; ++k) {
    const float a0 = A[r0][k];
    const float a1 = A[r0 + 16][k];
    const float4 w0 = *reinterpret_cast<const float4*>(&W1[(size_t)k * ODIM + c]);
    const float4 w1 = *reinterpret_cast<const float4*>(&W1[(size_t)k * ODIM + c + 4]);
    const float w[8] = {w0.x, w0.y, w0.z, w0.w, w1.x, w1.y, w1.z, w1.w};
#pragma unroll
    for (int j = 0; j < 8; ++j) {
      acc[0][j] = fmaf(a0, w[j], acc[0][j]);
      acc[1][j] = fmaf(a1, w[j], acc[1][j]);
    }
  }
  {
    const float4 bb0 = *reinterpret_cast<const float4*>(&b1[c]);
    const float4 bb1 = *reinterpret_cast<const float4*>(&b1[c + 4]);
    const float bb[8] = {bb0.x, bb0.y, bb0.z, bb0.w, bb1.x, bb1.y, bb1.z, bb1.w};
#pragma unroll
    for (int i = 0; i < 2; ++i) {
      const int rr = r0 + 16 * i;
      float4 h0 = make_float4(fmaxf(acc[i][0] + bb[0], 0.f), fmaxf(acc[i][1] + bb[1], 0.f),
                              fmaxf(acc[i][2] + bb[2], 0.f), fmaxf(acc[i][3] + bb[3], 0.f));
      float4 h1 = make_float4(fmaxf(acc[i][4] + bb[4], 0.f), fmaxf(acc[i][5] + bb[5], 0.f),
                              fmaxf(acc[i][6] + bb[6], 0.f), fmaxf(acc[i][7] + bb[7], 0.f));
      *reinterpret_cast<float4*>(&H[rr][c]) = h0;
      *reinterpret_cast<float4*>(&H[rr][c + 4]) = h1;
    }
  }
  __syncthreads();

#pragma unroll
  for (int i = 0; i < 2; ++i)
#pragma unroll
    for (int j = 0; j < 8; ++j) acc[i][j] = 0.0f;

#pragma unroll 2
  for (int k = 0; k < ODIM; ++k) {
    const float a0 = H[r0][k];
    const float a1 = H[r0 + 16][k];
    const float4 w0 = *reinterpret_cast<const float4*>(&W2[(size_t)k * ODIM + c]);
    const float4 w1 = *reinterpret_cast<const float4*>(&W2[(size_t)k * ODIM + c + 4]);
    const float w[8] = {w0.x, w0.y, w0.z, w0.w, w1.x, w1.y, w1.z, w1.w};
#pragma unroll
    for (int j = 0; j < 8; ++j) {
      acc[0][j] = fmaf(a0, w[j], acc[0][j]);
      acc[1][j] = fmaf(a1, w[j], acc[1][j]);
    }
  }
  {
    const float4 bb0 = *reinterpret_cast<const float4*>(&b2[c]);
    const float4 bb1 = *reinterpret_cast<const float4*>(&b2[c + 4]);
    const float bb[8] = {bb0.x, bb0.y, bb0.z, bb0.w, bb1.x, bb1.y, bb1.z, bb1.w};
#pragma unroll
    for (int i = 0; i < 2; ++i) {
      const size_t row = (size_t)(row0 + r0 + 16 * i);
      float4 o0 = make_float4(fmaxf(acc[i][0] + bb[0], 0.f), fmaxf(acc[i][1] + bb[1], 0.f),
                              fmaxf(acc[i][2] + bb[2], 0.f), fmaxf(acc[i][3] + bb[3], 0.f));
      float4 o1 = make_float4(fmaxf(acc[i][4] + bb[4], 0.f), fmaxf(acc[i][5] + bb[5], 0.f),
                              fmaxf(acc[i][6] + bb[6], 0.f), fmaxf(acc[i][7] + bb[7], 0.f));
      *reinterpret_cast<float4*>(&out[row * ODIM + c]) = o0;
      *reinterpret_cast<float4*>(&out[row * ODIM + c + 4]) = o1;
    }
  }
}

// ---------------------------------------------------------------------------
extern "C" void kernel_launch(void* const* d_in, const int* in_sizes, int n_in,
                              void* d_out, int out_size, void* d_ws, size_t ws_size,
                              hipStream_t stream) {
  const float* points   = (const float*)d_in[0];
  const float* features = (const float*)d_in[1];
  const int*   mask     = (const int*)d_in[2];
  const float* W1       = (const float*)d_in[3];
  const float* b1       = (const float*)d_in[4];
  const float* W2       = (const float*)d_in[5];
  const float* b2       = (const float*)d_in[6];
  float* out = (float*)d_out;

  // exact density threshold: dist < R  <=>  d2c < DENS_T  (validated R4/R5)
  const double Rd   = (double)0.02f;
  const double midd = Rd - ldexp(1.0, -30);     // halfway(pred(R), R)
  const double Td   = midd * midd;
  float densT = (float)Td;
  if ((double)densT <= Td) densT = nextafterf(densT, 1.0f);
  const float collectT = 0.0935f * 0.0935f;     // collect radius^2 (< (3h)^2 with margin)
  const float thrCheck = 0.0934f;               // completeness check on dist9

  // ws layout (256B aligned). countBuf+flags2+listCnt+ctrAcc contiguous for one memset.
  char* w = (char*)d_ws;
  size_t off = 0;
  auto take = [&](size_t bytes) { char* p = w + off; off = (off + bytes + 255) & ~(size_t)255; return p; };
  float*  geomBuf   = (float*)take((size_t)NQ_ALL * 6 * 4);
  float*  centerBuf = (float*)take(2 * 16);
  char*   zero0     = (char*)take(0);
  int*    countBuf  = (int*)take((size_t)B_SZ * NCELL * 4);
  int*    flags2Buf = (int*)take((size_t)NQ_ALL * 4);
  int*    listCnt   = (int*)take(4);
  double* ctrAcc    = (double*)take((size_t)B_SZ * 4 * 8);
  char*   zero1     = (char*)take(0);
  int*    startBuf  = (int*)take((size_t)B_SZ * (NCELL + 1) * 4);
  int*    curBuf    = (int*)take((size_t)B_SZ * NCELL * 4);
  float4* sortedBuf = (float4*)take((size_t)B_SZ * N_PTS * 16);
  int*    listBuf   = (int*)take((size_t)NQ_ALL * 4);
  (void)ws_size;

  hipMemsetAsync(zero0, 0, (size_t)(zero1 - zero0), stream);
  k_build<<<NQ_ALL / 256, 256, 0, stream>>>(points, mask, countBuf, ctrAcc);
  k_scan<<<B_SZ, 1024, 0, stream>>>(countBuf, startBuf, curBuf, ctrAcc, centerBuf);
  k_scatter<<<NQ_ALL / 256, 256, 0, stream>>>(points, mask, curBuf, sortedBuf);
  k_collect<<<dim3(NSUPER, B_SZ), 128, 0, stream>>>(points, sortedBuf, startBuf, centerBuf,
                                                    geomBuf, listBuf, listCnt,
                                                    collectT, densT, thrCheck);
  k_wavefb<<<1024, 64, 0, stream>>>(points, sortedBuf, startBuf, centerBuf,
                                    geomBuf, flags2Buf, listBuf, listCnt);
  k_fallback<<<dim3(N_PTS / 256, B_SZ), 256, 0, stream>>>(points, sortedBuf, startBuf,
                                                          centerBuf, geomBuf, flags2Buf);
  k_mlp<<<NQ_ALL / MROWS, 256, 0, stream>>>(features, geomBuf, W1, b1, W2, b2, out);
}